// Round 9
// baseline (201.509 us; speedup 1.0000x reference)
//
#include <hip/hip_runtime.h>

// ---------------------------------------------------------------------------
// VQ-VAE forward, f32, NHWC intermediates (channels innermost -> float4 I/O).
//  K1 conv1 (1->16) co-split -> y1 PADDED [64][130][130][16] (interior only)
//  K2 bn1 reduce (16 blocks, transposed partials)
//  K2b padfill: halo := (-sh-1)/sc  => relu(bn1(halo)) == 0 exactly
//  K3 conv2 (16->4), NO bounds checks (padded input), bn1+relu on read -> y2
//  K4 bn2 reduce
//  K5 VQ fused -> h3
//  K6 loss finalize -> d_out[4194304]
//  K7 convT1 (4->16) co-split -> h4 (reuses y1 region, unpadded)
//  K8 bn3 reduce (16 blocks)
//  K9 convT2 (16->1), LDS-tiled -> d_out
// R8 lesson: conv zero-padding applies to the ACTIVATION, not raw y1 — halo
// must hold the value whose bn+relu is zero, so it is filled after bn1 stats.
// ---------------------------------------------------------------------------

#define Y1_N 270400            // 130*130*16 floats per image
#define Y1_ROW 2080            // 130*16

// ---------------- K2b: fill halo with activation-zero value ----------------
__global__ __launch_bounds__(256) void k_padfill(
    float* __restrict__ y1, const float* __restrict__ bnp)
{
  const int idx = blockIdx.x * 256 + threadIdx.x;   // exactly 129*256 = 33024
  const int n = idx / 516, b = idx - n * 516;
  int row, col;
  if (b < 260) { row = (b < 130) ? 0 : 129; col = (b < 130) ? b : b - 130; }
  else { int b2 = b - 260; row = 1 + (b2 >> 1); col = (b2 & 1) ? 129 : 0; }
  float4* p = (float4*)(y1 + (size_t)n * Y1_N + (row * 130 + col) * 16);
#pragma unroll
  for (int g = 0; g < 4; ++g) {
    float4 sc = *(const float4*)(bnp + (g << 2));
    float4 sh = *(const float4*)(bnp + 16 + (g << 2));
    float4 v;
    v.x = (sc.x != 0.f) ? (-sh.x - 1.f) / sc.x : 0.f;
    v.y = (sc.y != 0.f) ? (-sh.y - 1.f) / sc.y : 0.f;
    v.z = (sc.z != 0.f) ? (-sh.z - 1.f) / sc.z : 0.f;
    v.w = (sc.w != 0.f) ? (-sh.w - 1.f) / sc.w : 0.f;
    p[g] = v;
  }
}

// ---------------- K1: conv1 co-split + per-channel stats -------------------
__global__ __launch_bounds__(256) void k_conv1(
    const float* __restrict__ x, const float* __restrict__ w1,
    const float* __restrict__ b1, float* __restrict__ y1,
    float* __restrict__ part)
{
  __shared__ float s_w[256];     // [k16][c16]
  __shared__ float s_b[16];
  const int tid = threadIdx.x;
  { int c = tid >> 4, k = tid & 15; s_w[k * 16 + c] = w1[c * 16 + k]; }
  if (tid < 16) s_b[tid] = b1[tid];
  __syncthreads();

  const int lane = tid & 63;
  const int cb = lane & 3;                  // channel-quad 0..3
  const int psl = lane >> 2;                // pixel slot 0..15
  const int gwave = (blockIdx.x << 2) | (tid >> 6);   // 4096 waves
  const int base = gwave << 8;              // 256 pixels per wave
  const int n = base >> 14;
  const float* xb = x + n * 65536;
  float* yn = y1 + (size_t)n * Y1_N;
  const float4* s_w4 = (const float4*)s_w;
  const float4 bv = ((const float4*)s_b)[cb];

  float lsum[4] = {0.f, 0.f, 0.f, 0.f}, lsq[4] = {0.f, 0.f, 0.f, 0.f};

#pragma unroll 1
  for (int i = 0; i < 16; ++i) {
    const int pos = base + (i << 4) + psl;
    const int r = pos & 16383;
    const int oh = r >> 7, ow = r & 127;
    const int ihb = oh * 2 - 1, iwb = ow * 2 - 1;

    float a0 = bv.x, a1 = bv.y, a2 = bv.z, a3 = bv.w;
#pragma unroll
    for (int kh = 0; kh < 4; ++kh) {
      int ih = ihb + kh; bool okh = (unsigned)ih < 256u;
#pragma unroll
      for (int kw = 0; kw < 4; ++kw) {
        int iw = iwb + kw;
        bool ok = okh && ((unsigned)iw < 256u);
        float v = ok ? xb[ih * 256 + iw] : 0.f;
        float4 wv = s_w4[(kh * 4 + kw) * 4 + cb];
        a0 = fmaf(v, wv.x, a0); a1 = fmaf(v, wv.y, a1);
        a2 = fmaf(v, wv.z, a2); a3 = fmaf(v, wv.w, a3);
      }
    }
    *(float4*)(yn + (size_t)(oh + 1) * Y1_ROW + (ow + 1) * 16 + cb * 4) =
        make_float4(a0, a1, a2, a3);
    lsum[0] += a0; lsum[1] += a1; lsum[2] += a2; lsum[3] += a3;
    lsq[0] = fmaf(a0, a0, lsq[0]); lsq[1] = fmaf(a1, a1, lsq[1]);
    lsq[2] = fmaf(a2, a2, lsq[2]); lsq[3] = fmaf(a3, a3, lsq[3]);
  }

  // transposed partials: part[stat 0..31][4096]
#pragma unroll
  for (int j = 0; j < 4; ++j) {
    float sv = lsum[j], qv = lsq[j];
#pragma unroll
    for (int d = 4; d < 64; d <<= 1) { sv += __shfl_down(sv, d); qv += __shfl_down(qv, d); }
    if (lane < 4) {
      part[(lane * 4 + j) * 4096 + gwave]        = sv;
      part[(16 + lane * 4 + j) * 4096 + gwave]   = qv;
    }
  }
}

// ---------------- K2/K8: 16-channel BN reduce, 16 blocks -------------------
__global__ __launch_bounds__(256) void k_bnred16(
    const float* __restrict__ part, const float* __restrict__ g,
    const float* __restrict__ bt, float* __restrict__ sc,
    float* __restrict__ sh, double invN)
{
  __shared__ double sd[256], sqd[256];
  const int c = blockIdx.x, tid = threadIdx.x;
  const float4* ps = (const float4*)(part + c * 4096);
  const float4* pq = (const float4*)(part + (16 + c) * 4096);
  double S = 0.0, Q = 0.0;
#pragma unroll
  for (int i = 0; i < 4; ++i) {
    float4 v = ps[tid * 4 + i];
    S += (double)v.x + (double)v.y + (double)v.z + (double)v.w;
    float4 q = pq[tid * 4 + i];
    Q += (double)q.x + (double)q.y + (double)q.z + (double)q.w;
  }
  sd[tid] = S; sqd[tid] = Q;
  __syncthreads();
  for (int off = 128; off > 0; off >>= 1) {
    if (tid < off) { sd[tid] += sd[tid + off]; sqd[tid] += sqd[tid + off]; }
    __syncthreads();
  }
  if (tid == 0) {
    double mean = sd[0] * invN;
    double var  = sqd[0] * invN - mean * mean;
    float scale = (float)((double)g[c] / sqrt(var + 1e-5));
    sc[c] = scale;
    sh[c] = bt[c] - (float)mean * scale;
  }
}

// ---------------- K4: 4-channel BN reduce (1 block, small) -----------------
__global__ __launch_bounds__(256) void k_bnred4(
    const float* __restrict__ part, const float* __restrict__ g,
    const float* __restrict__ bt, float* __restrict__ sc,
    float* __restrict__ sh, double invN)
{
  __shared__ double sd[256], sq[256];
  const int tid = threadIdx.x;
  int c = tid & 3, chunk = tid >> 2;   // 64 chunks
  double S = 0.0, Q = 0.0;
#pragma unroll 4
  for (int b = chunk; b < 1024; b += 64) {
    S += (double)part[b * 8 + c];
    Q += (double)part[b * 8 + 4 + c];
  }
  sd[tid] = S; sq[tid] = Q;
  __syncthreads();
  if (chunk == 0) {
    for (int j = 1; j < 64; ++j) { S += sd[j * 4 + c]; Q += sq[j * 4 + c]; }
    double mean = S * invN;
    double var  = Q * invN - mean * mean;
    float scale = (float)((double)g[c] / sqrt(var + 1e-5));
    sc[c] = scale;
    sh[c] = bt[c] - (float)mean * scale;
  }
}

// ---------------- K3: conv2 on padded y1, zero bounds checks ---------------
__global__ __launch_bounds__(256) void k_conv2(
    const float* __restrict__ y1, const float* __restrict__ w2,
    const float* __restrict__ b2, const float* __restrict__ bnp,
    float* __restrict__ y2, float* __restrict__ part)
{
  __shared__ float s_w[1024];        // [k16][ci16][co4]
  __shared__ float s_sc[16], s_sh[16];
  __shared__ float s_b[4];
  __shared__ float s_sum[4], s_sq[4];
  const int tid = threadIdx.x;
  for (int i = tid; i < 1024; i += 256) {
    int co = i & 3, ci = (i >> 2) & 15, k = i >> 6;
    int kh = k >> 2, kw = k & 3;
    s_w[i] = w2[((co * 16 + ci) * 4 + kh) * 4 + kw];
  }
  if (tid < 16) { s_sc[tid] = bnp[tid]; s_sh[tid] = bnp[16 + tid]; }
  if (tid < 4)  { s_b[tid] = b2[tid]; s_sum[tid] = 0.f; s_sq[tid] = 0.f; }
  __syncthreads();

  const int pos = blockIdx.x * 256 + tid;      // < 262,144
  const int n = pos >> 12, r = pos & 4095;
  const int oh = r >> 6, ow = r & 63;
  const float* yb = y1 + (size_t)n * Y1_N + (size_t)(oh * 2) * Y1_ROW + (ow * 2) * 16;

  float acc[4];
#pragma unroll
  for (int c = 0; c < 4; ++c) acc[c] = s_b[c];

  const float4* s_w4 = (const float4*)s_w;
#pragma unroll
  for (int kh = 0; kh < 4; ++kh) {
    const float* rowp = yb + kh * Y1_ROW;
#pragma unroll
    for (int kw = 0; kw < 4; ++kw) {
      const float4* p4 = (const float4*)(rowp + kw * 16);
      int kbase = ((kh << 2) | kw) << 4;
#pragma unroll
      for (int g = 0; g < 4; ++g) {
        float4 v = p4[g];
        float a0 = fmaxf(fmaf(v.x, s_sc[g*4+0], s_sh[g*4+0]), 0.f);
        float a1 = fmaxf(fmaf(v.y, s_sc[g*4+1], s_sh[g*4+1]), 0.f);
        float a2 = fmaxf(fmaf(v.z, s_sc[g*4+2], s_sh[g*4+2]), 0.f);
        float a3 = fmaxf(fmaf(v.w, s_sc[g*4+3], s_sh[g*4+3]), 0.f);
        float4 w0 = s_w4[kbase + g*4 + 0];
        float4 w1 = s_w4[kbase + g*4 + 1];
        float4 w2v = s_w4[kbase + g*4 + 2];
        float4 w3 = s_w4[kbase + g*4 + 3];
        acc[0] = fmaf(a0, w0.x, fmaf(a1, w1.x, fmaf(a2, w2v.x, fmaf(a3, w3.x, acc[0]))));
        acc[1] = fmaf(a0, w0.y, fmaf(a1, w1.y, fmaf(a2, w2v.y, fmaf(a3, w3.y, acc[1]))));
        acc[2] = fmaf(a0, w0.z, fmaf(a1, w1.z, fmaf(a2, w2v.z, fmaf(a3, w3.z, acc[2]))));
        acc[3] = fmaf(a0, w0.w, fmaf(a1, w1.w, fmaf(a2, w2v.w, fmaf(a3, w3.w, acc[3]))));
      }
    }
  }
  *(float4*)(y2 + (size_t)pos * 4) = make_float4(acc[0], acc[1], acc[2], acc[3]);

  const int lane = tid & 63;
#pragma unroll
  for (int c = 0; c < 4; ++c) {
    float sv = acc[c], qv = acc[c] * acc[c];
#pragma unroll
    for (int d = 32; d > 0; d >>= 1) { sv += __shfl_down(sv, d); qv += __shfl_down(qv, d); }
    if (lane == 0) { atomicAdd(&s_sum[c], sv); atomicAdd(&s_sq[c], qv); }
  }
  __syncthreads();
  if (tid < 8) part[blockIdx.x * 8 + tid] = (tid < 4) ? s_sum[tid] : s_sq[tid - 4];
}

// ---------------- K5: fused VQ -------------------------------------------
__global__ __launch_bounds__(256) void k_vq(
    const float* __restrict__ y2, const float* __restrict__ bnp2,
    const float* __restrict__ pw, const float* __restrict__ pb,
    const float* __restrict__ cb, const float* __restrict__ postw,
    const float* __restrict__ postb, float* __restrict__ h3,
    float* __restrict__ lpart)
{
  const int tid = threadIdx.x;
  const int pos = blockIdx.x * 256 + tid;     // < 262,144
  float4 v = *(const float4*)(y2 + (size_t)pos * 4);
  float aa0 = fmaxf(fmaf(v.x, bnp2[0], bnp2[4]), 0.f);
  float aa1 = fmaxf(fmaf(v.y, bnp2[1], bnp2[5]), 0.f);
  float aa2 = fmaxf(fmaf(v.z, bnp2[2], bnp2[6]), 0.f);
  float aa3 = fmaxf(fmaf(v.w, bnp2[3], bnp2[7]), 0.f);
  float z0 = pb[0] + aa0*pw[0] + aa1*pw[1] + aa2*pw[2] + aa3*pw[3];
  float z1 = pb[1] + aa0*pw[4] + aa1*pw[5] + aa2*pw[6] + aa3*pw[7];

  float best = 3.4e38f, q0 = 0.f, q1 = 0.f;
#pragma unroll
  for (int k = 0; k < 3; ++k) {
    float c0 = cb[2 * k], c1 = cb[2 * k + 1];
    float dx = z0 - c0, dy = z1 - c1;
    float d = dx * dx + dy * dy;
    if (d < best) { best = d; q0 = c0; q1 = c1; }   // strict < == first-min
  }
  float dl = (q0 - z0) * (q0 - z0) + (q1 - z1) * (q1 - z1);

  float4 hv;
  hv.x = fmaf(q0, postw[0], fmaf(q1, postw[1], postb[0]));
  hv.y = fmaf(q0, postw[2], fmaf(q1, postw[3], postb[1]));
  hv.z = fmaf(q0, postw[4], fmaf(q1, postw[5], postb[2]));
  hv.w = fmaf(q0, postw[6], fmaf(q1, postw[7], postb[3]));
  *(float4*)(h3 + (size_t)pos * 4) = hv;

  float s = dl;
#pragma unroll
  for (int d = 32; d > 0; d >>= 1) s += __shfl_down(s, d);
  __shared__ float ws4[4];
  if ((tid & 63) == 0) ws4[tid >> 6] = s;
  __syncthreads();
  if (tid == 0) lpart[blockIdx.x] = (ws4[0] + ws4[1]) + (ws4[2] + ws4[3]);
}

__global__ __launch_bounds__(256) void k_lossfin(
    const float* __restrict__ lpart, float* __restrict__ outp)
{
  const int tid = threadIdx.x;
  float s = lpart[tid] + lpart[tid + 256] + lpart[tid + 512] + lpart[tid + 768];
#pragma unroll
  for (int d = 32; d > 0; d >>= 1) s += __shfl_down(s, d);
  __shared__ float ws4[4];
  if ((tid & 63) == 0) ws4[tid >> 6] = s;
  __syncthreads();
  if (tid == 0) {
    double tot = (double)ws4[0] + (double)ws4[1] + (double)ws4[2] + (double)ws4[3];
    outp[0] = (float)(1.2 * tot / 524288.0);   // (1+BETA) * mean over B*N*C
  }
}

// ---------------- K7: convT1 (4->16) co-split + stats ----------------------
__global__ __launch_bounds__(256) void k_convt1(
    const float* __restrict__ h3, const float* __restrict__ w,
    const float* __restrict__ bias, float* __restrict__ h4,
    float* __restrict__ part)
{
  __shared__ float s_w[1024];   // [k16][ci4][co16]
  __shared__ float s_b[16];
  const int tid = threadIdx.x;
  for (int i = tid; i < 1024; i += 256) {
    int co = i & 15, ci = (i >> 4) & 3, k = i >> 6;
    int kh = k >> 2, kw = k & 3;
    s_w[i] = w[((co * 4 + ci) * 4 + kh) * 4 + kw];
  }
  if (tid < 16) s_b[tid] = bias[tid];
  __syncthreads();

  const int lane = tid & 63;
  const int cb = lane & 3;
  const int psl = lane >> 2;
  const int gwave = (blockIdx.x << 2) | (tid >> 6);   // 4096 waves
  const int base = gwave << 8;
  const int n = base >> 14;
  const float* hb = h3 + (size_t)n * 16384;
  const float4* s_w4 = (const float4*)s_w;   // idx = k*16 + ci*4 + cb
  const float4 bv = ((const float4*)s_b)[cb];

  float lsum[4] = {0.f, 0.f, 0.f, 0.f}, lsq[4] = {0.f, 0.f, 0.f, 0.f};

#pragma unroll 1
  for (int i = 0; i < 16; ++i) {
    const int pos = base + (i << 4) + psl;
    const int r = pos & 16383;
    const int oh = r >> 7, ow = r & 127;
    const int ohp = oh & 1, owp = ow & 1;

    float a0 = bv.x, a1 = bv.y, a2 = bv.z, a3 = bv.w;
#pragma unroll
    for (int th = 0; th < 2; ++th) {
      int kh = th * 2 + ohp;
      int ih = (oh + kh - 2) >> 1;
      bool okh = (unsigned)ih < 64u;
#pragma unroll
      for (int tw = 0; tw < 2; ++tw) {
        int kw = tw * 2 + owp;
        int iw = (ow + kw - 2) >> 1;
        bool ok = okh && ((unsigned)iw < 64u);
        if (ok) {
          float4 v = *(const float4*)(hb + (ih * 64 + iw) * 4);
          int k16 = (kh * 4 + kw) * 16;
          float4 w0 = s_w4[k16 + 0 * 4 + cb];
          float4 w1 = s_w4[k16 + 1 * 4 + cb];
          float4 w2 = s_w4[k16 + 2 * 4 + cb];
          float4 w3 = s_w4[k16 + 3 * 4 + cb];
          a0 = fmaf(v.x, w0.x, fmaf(v.y, w1.x, fmaf(v.z, w2.x, fmaf(v.w, w3.x, a0))));
          a1 = fmaf(v.x, w0.y, fmaf(v.y, w1.y, fmaf(v.z, w2.y, fmaf(v.w, w3.y, a1))));
          a2 = fmaf(v.x, w0.z, fmaf(v.y, w1.z, fmaf(v.z, w2.z, fmaf(v.w, w3.z, a2))));
          a3 = fmaf(v.x, w0.w, fmaf(v.y, w1.w, fmaf(v.z, w2.w, fmaf(v.w, w3.w, a3))));
        }
      }
    }
    *(float4*)(h4 + (size_t)pos * 16 + cb * 4) = make_float4(a0, a1, a2, a3);
    lsum[0] += a0; lsum[1] += a1; lsum[2] += a2; lsum[3] += a3;
    lsq[0] = fmaf(a0, a0, lsq[0]); lsq[1] = fmaf(a1, a1, lsq[1]);
    lsq[2] = fmaf(a2, a2, lsq[2]); lsq[3] = fmaf(a3, a3, lsq[3]);
  }

#pragma unroll
  for (int j = 0; j < 4; ++j) {
    float sv = lsum[j], qv = lsq[j];
#pragma unroll
    for (int d = 4; d < 64; d <<= 1) { sv += __shfl_down(sv, d); qv += __shfl_down(qv, d); }
    if (lane < 4) {
      part[(lane * 4 + j) * 4096 + gwave]      = sv;
      part[(16 + lane * 4 + j) * 4096 + gwave] = qv;
    }
  }
}

// ---------------- K9: convT2 (16->1), LDS-tiled ----------------------------
__global__ __launch_bounds__(256) void k_convt2(
    const float* __restrict__ h4, const float* __restrict__ w,
    const float* __restrict__ bias, const float* __restrict__ bnp,
    float* __restrict__ out)
{
  __shared__ float4 s_t[4][18][19];
  __shared__ float s_w[256];     // [ci16][kh4][kw4]
  const int tid = threadIdx.x;
  s_w[tid] = w[tid];

  const int bx = blockIdx.x;
  const int n = bx >> 6;
  const int tile = bx & 63;
  const int ta = ((tile >> 3) << 4);   // input tile origin row
  const int tb = ((tile & 7) << 4);    // input tile origin col
  const float* hb = h4 + (size_t)n * 262144;

  for (int i = tid; i < 1296; i += 256) {     // 324 positions x 4 groups
    int g = i & 3, p = i >> 2;
    int row = p / 18, col = p - row * 18;
    int ih = ta - 1 + row, iw = tb - 1 + col;
    float4 t = make_float4(0.f, 0.f, 0.f, 0.f);
    if (((unsigned)ih < 128u) && ((unsigned)iw < 128u)) {
      float4 v   = *(const float4*)(hb + ((ih << 7) + iw) * 16 + (g << 2));
      float4 scv = *(const float4*)(bnp + 40 + (g << 2));
      float4 shv = *(const float4*)(bnp + 56 + (g << 2));
      t.x = fmaxf(fmaf(v.x, scv.x, shv.x), 0.f);
      t.y = fmaxf(fmaf(v.y, scv.y, shv.y), 0.f);
      t.z = fmaxf(fmaf(v.z, scv.z, shv.z), 0.f);
      t.w = fmaxf(fmaf(v.w, scv.w, shv.w), 0.f);
    }
    s_t[g][row][col] = t;
  }
  __syncthreads();

  const int a = tid >> 4, b = tid & 15;
  const float4* s_w4 = (const float4*)s_w;
  float acc00 = 0.f, acc01 = 0.f, acc10 = 0.f, acc11 = 0.f;

#pragma unroll
  for (int g = 0; g < 4; ++g) {
    float4 v00 = s_t[g][a  ][b  ], v01 = s_t[g][a  ][b+1], v02 = s_t[g][a  ][b+2];
    float4 v10 = s_t[g][a+1][b  ], v11 = s_t[g][a+1][b+1], v12 = s_t[g][a+1][b+2];
    float4 v20 = s_t[g][a+2][b  ], v21 = s_t[g][a+2][b+1], v22 = s_t[g][a+2][b+2];
#pragma unroll
    for (int j = 0; j < 4; ++j) {
      int ci = g * 4 + j;
      float4 r0 = s_w4[ci*4+0], r1 = s_w4[ci*4+1];
      float4 r2 = s_w4[ci*4+2], r3 = s_w4[ci*4+3];
      float a00 = (j==0)?v00.x:(j==1)?v00.y:(j==2)?v00.z:v00.w;
      float a01 = (j==0)?v01.x:(j==1)?v01.y:(j==2)?v01.z:v01.w;
      float a02 = (j==0)?v02.x:(j==1)?v02.y:(j==2)?v02.z:v02.w;
      float a10 = (j==0)?v10.x:(j==1)?v10.y:(j==2)?v10.z:v10.w;
      float a11 = (j==0)?v11.x:(j==1)?v11.y:(j==2)?v11.z:v11.w;
      float a12 = (j==0)?v12.x:(j==1)?v12.y:(j==2)?v12.z:v12.w;
      float a20 = (j==0)?v20.x:(j==1)?v20.y:(j==2)?v20.z:v20.w;
      float a21 = (j==0)?v21.x:(j==1)?v21.y:(j==2)?v21.z:v21.w;
      float a22 = (j==0)?v22.x:(j==1)?v22.y:(j==2)?v22.z:v22.w;
      acc00 += a00*r0.x + a01*r0.z + a10*r2.x + a11*r2.z;
      acc01 += a01*r0.y + a02*r0.w + a11*r2.y + a12*r2.w;
      acc10 += a10*r1.x + a11*r1.z + a20*r3.x + a21*r3.z;
      acc11 += a11*r1.y + a12*r1.w + a21*r3.y + a22*r3.w;
    }
  }
  const float bv = bias[0];
  const int A = ta + a, B = tb + b;
  float* ob = out + n * 65536 + (2 * A) * 256 + 2 * B;
  *(float2*)ob         = make_float2(acc00 + bv, acc01 + bv);
  *(float2*)(ob + 256) = make_float2(acc10 + bv, acc11 + bv);
}

// ---------------------------------------------------------------------------
extern "C" void kernel_launch(void* const* d_in, const int* in_sizes, int n_in,
                              void* d_out, int out_size, void* d_ws, size_t ws_size,
                              hipStream_t stream)
{
  const float* x      = (const float*)d_in[0];
  const float* enc_w1 = (const float*)d_in[1];
  const float* enc_b1 = (const float*)d_in[2];
  const float* bn1_g  = (const float*)d_in[3];
  const float* bn1_b  = (const float*)d_in[4];
  const float* enc_w2 = (const float*)d_in[5];
  const float* enc_b2 = (const float*)d_in[6];
  const float* bn2_g  = (const float*)d_in[7];
  const float* bn2_b  = (const float*)d_in[8];
  const float* pre_w  = (const float*)d_in[9];
  const float* pre_b  = (const float*)d_in[10];
  const float* cb     = (const float*)d_in[11];
  const float* post_w = (const float*)d_in[12];
  const float* post_b = (const float*)d_in[13];
  const float* dec_w1 = (const float*)d_in[14];
  const float* dec_b1 = (const float*)d_in[15];
  const float* bn3_g  = (const float*)d_in[16];
  const float* bn3_b  = (const float*)d_in[17];
  const float* dec_w2 = (const float*)d_in[18];
  const float* dec_b2 = (const float*)d_in[19];

  float* ws  = (float*)d_ws;
  float* y1  = ws;                       // padded: 17,305,600 f -- h4 reuses region
  float* y2  = ws + 17305600;            //  1,048,576 f
  float* h3  = ws + 18354176;            //  1,048,576 f
  float* p1  = ws + 19402752;            //    131,072 f ([32][4096]) -- also p3
  float* p2  = ws + 19533824;            //      8,192 f ([1024][8])
  float* lp  = ws + 19542016;            //      1,024 f
  float* bnp = ws + 19543040;            //         72 f (sc1,sh1,sc2,sh2,sc3,sh3)
  float* h4  = y1;                       // unpadded [64][128][128][16] view
  float* p3  = p1;
  float* out = (float*)d_out;

  k_conv1<<<1024, 256, 0, stream>>>(x, enc_w1, enc_b1, y1, p1);
  k_bnred16<<<16, 256, 0, stream>>>(p1, bn1_g, bn1_b, bnp, bnp + 16, 1.0 / 1048576.0);
  k_padfill<<<129, 256, 0, stream>>>(y1, bnp);
  k_conv2<<<1024, 256, 0, stream>>>(y1, enc_w2, enc_b2, bnp, y2, p2);
  k_bnred4<<<1, 256, 0, stream>>>(p2, bn2_g, bn2_b, bnp + 32, bnp + 36, 1.0 / 262144.0);
  k_vq<<<1024, 256, 0, stream>>>(y2, bnp + 32, pre_w, pre_b, cb, post_w, post_b, h3, lp);
  k_lossfin<<<1, 256, 0, stream>>>(lp, out + 4194304);
  k_convt1<<<1024, 256, 0, stream>>>(h3, dec_w1, dec_b1, h4, p3);
  k_bnred16<<<16, 256, 0, stream>>>(p3, bn3_g, bn3_b, bnp + 40, bnp + 56, 1.0 / 1048576.0);
  k_convt2<<<4096, 256, 0, stream>>>(h4, dec_w2, dec_b2, bnp, out);
}

// Round 10
// 148.023 us; speedup vs baseline: 1.3613x; 1.3613x over previous
//
#include <hip/hip_runtime.h>

// ---------------------------------------------------------------------------
// VQ-VAE forward, f32, NHWC intermediates (channels innermost -> float4 I/O).
//  K1 conv1 (1->16) co-split -> y1 [64,128,128,16] (unpadded; R9 padding
//     experiment REVERTED: guard-free conv2 tripled FETCH 83->255MB)
//  K2 bn1 reduce (16 blocks, transposed partials [stat32][4096])
//  K3 conv2 (16->4), guarded reads (R6-proven), bn1+relu on read, XCD-swizzled
//  K4 bn2 reduce
//  K5 VQ fused -> h3
//  K6 loss finalize -> d_out[4194304]
//  K7 convT1 (4->16) co-split -> h4 (reuses y1)
//  K8 bn3 reduce (16 blocks)
//  K9 convT2 (16->1), LDS-tiled, XCD-swizzled -> d_out
// Swizzle: grid = 8*k, id = (bx&7)*k + (bx>>3) -> row-neighbor blocks share
// an XCD L2 (halo reuse). Bijective since grid % 8 == 0.
// ---------------------------------------------------------------------------

// ---------------- K1: conv1 co-split + per-channel stats -------------------
__global__ __launch_bounds__(256) void k_conv1(
    const float* __restrict__ x, const float* __restrict__ w1,
    const float* __restrict__ b1, float* __restrict__ y1,
    float* __restrict__ part)
{
  __shared__ float s_w[256];     // [k16][c16]
  __shared__ float s_b[16];
  const int tid = threadIdx.x;
  { int c = tid >> 4, k = tid & 15; s_w[k * 16 + c] = w1[c * 16 + k]; }
  if (tid < 16) s_b[tid] = b1[tid];
  __syncthreads();

  const int lane = tid & 63;
  const int cb = lane & 3;                  // channel-quad 0..3
  const int psl = lane >> 2;                // pixel slot 0..15
  const int gwave = (blockIdx.x << 2) | (tid >> 6);   // 4096 waves
  const int base = gwave << 8;              // 256 pixels per wave
  const int n = base >> 14;
  const float* xb = x + n * 65536;
  const float4* s_w4 = (const float4*)s_w;
  const float4 bv = ((const float4*)s_b)[cb];

  float lsum[4] = {0.f, 0.f, 0.f, 0.f}, lsq[4] = {0.f, 0.f, 0.f, 0.f};

#pragma unroll 1
  for (int i = 0; i < 16; ++i) {
    const int pos = base + (i << 4) + psl;
    const int r = pos & 16383;
    const int oh = r >> 7, ow = r & 127;
    const int ihb = oh * 2 - 1, iwb = ow * 2 - 1;

    float a0 = bv.x, a1 = bv.y, a2 = bv.z, a3 = bv.w;
#pragma unroll
    for (int kh = 0; kh < 4; ++kh) {
      int ih = ihb + kh; bool okh = (unsigned)ih < 256u;
#pragma unroll
      for (int kw = 0; kw < 4; ++kw) {
        int iw = iwb + kw;
        bool ok = okh && ((unsigned)iw < 256u);
        float v = ok ? xb[ih * 256 + iw] : 0.f;
        float4 wv = s_w4[(kh * 4 + kw) * 4 + cb];
        a0 = fmaf(v, wv.x, a0); a1 = fmaf(v, wv.y, a1);
        a2 = fmaf(v, wv.z, a2); a3 = fmaf(v, wv.w, a3);
      }
    }
    *(float4*)(y1 + (size_t)pos * 16 + cb * 4) = make_float4(a0, a1, a2, a3);
    lsum[0] += a0; lsum[1] += a1; lsum[2] += a2; lsum[3] += a3;
    lsq[0] = fmaf(a0, a0, lsq[0]); lsq[1] = fmaf(a1, a1, lsq[1]);
    lsq[2] = fmaf(a2, a2, lsq[2]); lsq[3] = fmaf(a3, a3, lsq[3]);
  }

  // transposed partials: part[stat 0..31][4096]
#pragma unroll
  for (int j = 0; j < 4; ++j) {
    float sv = lsum[j], qv = lsq[j];
#pragma unroll
    for (int d = 4; d < 64; d <<= 1) { sv += __shfl_down(sv, d); qv += __shfl_down(qv, d); }
    if (lane < 4) {
      part[(lane * 4 + j) * 4096 + gwave]      = sv;
      part[(16 + lane * 4 + j) * 4096 + gwave] = qv;
    }
  }
}

// ---------------- K2/K8: 16-channel BN reduce, 16 blocks -------------------
__global__ __launch_bounds__(256) void k_bnred16(
    const float* __restrict__ part, const float* __restrict__ g,
    const float* __restrict__ bt, float* __restrict__ sc,
    float* __restrict__ sh, double invN)
{
  __shared__ double sd[256], sqd[256];
  const int c = blockIdx.x, tid = threadIdx.x;
  const float4* ps = (const float4*)(part + c * 4096);
  const float4* pq = (const float4*)(part + (16 + c) * 4096);
  double S = 0.0, Q = 0.0;
#pragma unroll
  for (int i = 0; i < 4; ++i) {
    float4 v = ps[tid * 4 + i];
    S += (double)v.x + (double)v.y + (double)v.z + (double)v.w;
    float4 q = pq[tid * 4 + i];
    Q += (double)q.x + (double)q.y + (double)q.z + (double)q.w;
  }
  sd[tid] = S; sqd[tid] = Q;
  __syncthreads();
  for (int off = 128; off > 0; off >>= 1) {
    if (tid < off) { sd[tid] += sd[tid + off]; sqd[tid] += sqd[tid + off]; }
    __syncthreads();
  }
  if (tid == 0) {
    double mean = sd[0] * invN;
    double var  = sqd[0] * invN - mean * mean;
    float scale = (float)((double)g[c] / sqrt(var + 1e-5));
    sc[c] = scale;
    sh[c] = bt[c] - (float)mean * scale;
  }
}

// ---------------- K4: 4-channel BN reduce (1 block, small) -----------------
__global__ __launch_bounds__(256) void k_bnred4(
    const float* __restrict__ part, const float* __restrict__ g,
    const float* __restrict__ bt, float* __restrict__ sc,
    float* __restrict__ sh, double invN)
{
  __shared__ double sd[256], sq[256];
  const int tid = threadIdx.x;
  int c = tid & 3, chunk = tid >> 2;   // 64 chunks
  double S = 0.0, Q = 0.0;
#pragma unroll 4
  for (int b = chunk; b < 1024; b += 64) {
    S += (double)part[b * 8 + c];
    Q += (double)part[b * 8 + 4 + c];
  }
  sd[tid] = S; sq[tid] = Q;
  __syncthreads();
  if (chunk == 0) {
    for (int j = 1; j < 64; ++j) { S += sd[j * 4 + c]; Q += sq[j * 4 + c]; }
    double mean = S * invN;
    double var  = Q * invN - mean * mean;
    float scale = (float)((double)g[c] / sqrt(var + 1e-5));
    sc[c] = scale;
    sh[c] = bt[c] - (float)mean * scale;
  }
}

// ---------------- K3: conv2, bn1+relu fused on NHWC input, + stats ---------
// R6-proven guarded body; XCD swizzle so oh-neighbor blocks share an XCD L2.
__global__ __launch_bounds__(256) void k_conv2(
    const float* __restrict__ y1, const float* __restrict__ w2,
    const float* __restrict__ b2, const float* __restrict__ bnp,
    float* __restrict__ y2, float* __restrict__ part)
{
  __shared__ float s_w[1024];        // [k16][ci16][co4]
  __shared__ float s_sc[16], s_sh[16];
  __shared__ float s_b[4];
  __shared__ float s_sum[4], s_sq[4];
  const int tid = threadIdx.x;
  for (int i = tid; i < 1024; i += 256) {
    int co = i & 3, ci = (i >> 2) & 15, k = i >> 6;
    int kh = k >> 2, kw = k & 3;
    s_w[i] = w2[((co * 16 + ci) * 4 + kh) * 4 + kw];
  }
  if (tid < 16) { s_sc[tid] = bnp[tid]; s_sh[tid] = bnp[16 + tid]; }
  if (tid < 4)  { s_b[tid] = b2[tid]; s_sum[tid] = 0.f; s_sq[tid] = 0.f; }
  __syncthreads();

  // bijective XCD swizzle: grid 1024 = 8 * 128
  const int bid = ((blockIdx.x & 7) << 7) | (blockIdx.x >> 3);
  const int pos = bid * 256 + tid;             // < 262,144
  const int n = pos >> 12, r = pos & 4095;
  const int oh = r >> 6, ow = r & 63;
  const int ihb = oh * 2 - 1, iwb = ow * 2 - 1;
  const float* yb = y1 + (size_t)n * 262144;

  float acc[4];
#pragma unroll
  for (int c = 0; c < 4; ++c) acc[c] = s_b[c];

  const float4* s_w4 = (const float4*)s_w;
#pragma unroll
  for (int kh = 0; kh < 4; ++kh) {
    int ih = ihb + kh; bool okh = (unsigned)ih < 128u;
#pragma unroll
    for (int kw = 0; kw < 4; ++kw) {
      int iw = iwb + kw;
      bool ok = okh && ((unsigned)iw < 128u);
      if (ok) {
        const float4* p4 = (const float4*)(yb + (ih * 128 + iw) * 16);
        int kbase = (kh * 4 + kw) * 16;
#pragma unroll
        for (int g = 0; g < 4; ++g) {
          float4 v = p4[g];
          float a0 = fmaxf(fmaf(v.x, s_sc[g*4+0], s_sh[g*4+0]), 0.f);
          float a1 = fmaxf(fmaf(v.y, s_sc[g*4+1], s_sh[g*4+1]), 0.f);
          float a2 = fmaxf(fmaf(v.z, s_sc[g*4+2], s_sh[g*4+2]), 0.f);
          float a3 = fmaxf(fmaf(v.w, s_sc[g*4+3], s_sh[g*4+3]), 0.f);
          float4 w0 = s_w4[kbase + g*4 + 0];
          float4 w1 = s_w4[kbase + g*4 + 1];
          float4 w2v = s_w4[kbase + g*4 + 2];
          float4 w3 = s_w4[kbase + g*4 + 3];
          acc[0] = fmaf(a0, w0.x, fmaf(a1, w1.x, fmaf(a2, w2v.x, fmaf(a3, w3.x, acc[0]))));
          acc[1] = fmaf(a0, w0.y, fmaf(a1, w1.y, fmaf(a2, w2v.y, fmaf(a3, w3.y, acc[1]))));
          acc[2] = fmaf(a0, w0.z, fmaf(a1, w1.z, fmaf(a2, w2v.z, fmaf(a3, w3.z, acc[2]))));
          acc[3] = fmaf(a0, w0.w, fmaf(a1, w1.w, fmaf(a2, w2v.w, fmaf(a3, w3.w, acc[3]))));
        }
      }
    }
  }
  *(float4*)(y2 + (size_t)pos * 4) = make_float4(acc[0], acc[1], acc[2], acc[3]);

  const int lane = tid & 63;
#pragma unroll
  for (int c = 0; c < 4; ++c) {
    float sv = acc[c], qv = acc[c] * acc[c];
#pragma unroll
    for (int d = 32; d > 0; d >>= 1) { sv += __shfl_down(sv, d); qv += __shfl_down(qv, d); }
    if (lane == 0) { atomicAdd(&s_sum[c], sv); atomicAdd(&s_sq[c], qv); }
  }
  __syncthreads();
  if (tid < 8) part[bid * 8 + tid] = (tid < 4) ? s_sum[tid] : s_sq[tid - 4];
}

// ---------------- K5: fused VQ -------------------------------------------
__global__ __launch_bounds__(256) void k_vq(
    const float* __restrict__ y2, const float* __restrict__ bnp2,
    const float* __restrict__ pw, const float* __restrict__ pb,
    const float* __restrict__ cb, const float* __restrict__ postw,
    const float* __restrict__ postb, float* __restrict__ h3,
    float* __restrict__ lpart)
{
  const int tid = threadIdx.x;
  const int pos = blockIdx.x * 256 + tid;     // < 262,144
  float4 v = *(const float4*)(y2 + (size_t)pos * 4);
  float aa0 = fmaxf(fmaf(v.x, bnp2[0], bnp2[4]), 0.f);
  float aa1 = fmaxf(fmaf(v.y, bnp2[1], bnp2[5]), 0.f);
  float aa2 = fmaxf(fmaf(v.z, bnp2[2], bnp2[6]), 0.f);
  float aa3 = fmaxf(fmaf(v.w, bnp2[3], bnp2[7]), 0.f);
  float z0 = pb[0] + aa0*pw[0] + aa1*pw[1] + aa2*pw[2] + aa3*pw[3];
  float z1 = pb[1] + aa0*pw[4] + aa1*pw[5] + aa2*pw[6] + aa3*pw[7];

  float best = 3.4e38f, q0 = 0.f, q1 = 0.f;
#pragma unroll
  for (int k = 0; k < 3; ++k) {
    float c0 = cb[2 * k], c1 = cb[2 * k + 1];
    float dx = z0 - c0, dy = z1 - c1;
    float d = dx * dx + dy * dy;
    if (d < best) { best = d; q0 = c0; q1 = c1; }   // strict < == first-min
  }
  float dl = (q0 - z0) * (q0 - z0) + (q1 - z1) * (q1 - z1);

  float4 hv;
  hv.x = fmaf(q0, postw[0], fmaf(q1, postw[1], postb[0]));
  hv.y = fmaf(q0, postw[2], fmaf(q1, postw[3], postb[1]));
  hv.z = fmaf(q0, postw[4], fmaf(q1, postw[5], postb[2]));
  hv.w = fmaf(q0, postw[6], fmaf(q1, postw[7], postb[3]));
  *(float4*)(h3 + (size_t)pos * 4) = hv;

  float s = dl;
#pragma unroll
  for (int d = 32; d > 0; d >>= 1) s += __shfl_down(s, d);
  __shared__ float ws4[4];
  if ((tid & 63) == 0) ws4[tid >> 6] = s;
  __syncthreads();
  if (tid == 0) lpart[blockIdx.x] = (ws4[0] + ws4[1]) + (ws4[2] + ws4[3]);
}

__global__ __launch_bounds__(256) void k_lossfin(
    const float* __restrict__ lpart, float* __restrict__ outp)
{
  const int tid = threadIdx.x;
  float s = lpart[tid] + lpart[tid + 256] + lpart[tid + 512] + lpart[tid + 768];
#pragma unroll
  for (int d = 32; d > 0; d >>= 1) s += __shfl_down(s, d);
  __shared__ float ws4[4];
  if ((tid & 63) == 0) ws4[tid >> 6] = s;
  __syncthreads();
  if (tid == 0) {
    double tot = (double)ws4[0] + (double)ws4[1] + (double)ws4[2] + (double)ws4[3];
    outp[0] = (float)(1.2 * tot / 524288.0);   // (1+BETA) * mean over B*N*C
  }
}

// ---------------- K7: convT1 (4->16) co-split + stats ----------------------
__global__ __launch_bounds__(256) void k_convt1(
    const float* __restrict__ h3, const float* __restrict__ w,
    const float* __restrict__ bias, float* __restrict__ h4,
    float* __restrict__ part)
{
  __shared__ float s_w[1024];   // [k16][ci4][co16]
  __shared__ float s_b[16];
  const int tid = threadIdx.x;
  for (int i = tid; i < 1024; i += 256) {
    int co = i & 15, ci = (i >> 4) & 3, k = i >> 6;
    int kh = k >> 2, kw = k & 3;
    s_w[i] = w[((co * 4 + ci) * 4 + kh) * 4 + kw];
  }
  if (tid < 16) s_b[tid] = bias[tid];
  __syncthreads();

  const int lane = tid & 63;
  const int cb = lane & 3;
  const int psl = lane >> 2;
  const int gwave = (blockIdx.x << 2) | (tid >> 6);   // 4096 waves
  const int base = gwave << 8;
  const int n = base >> 14;
  const float* hb = h3 + (size_t)n * 16384;
  const float4* s_w4 = (const float4*)s_w;   // idx = k*16 + ci*4 + cb
  const float4 bv = ((const float4*)s_b)[cb];

  float lsum[4] = {0.f, 0.f, 0.f, 0.f}, lsq[4] = {0.f, 0.f, 0.f, 0.f};

#pragma unroll 1
  for (int i = 0; i < 16; ++i) {
    const int pos = base + (i << 4) + psl;
    const int r = pos & 16383;
    const int oh = r >> 7, ow = r & 127;
    const int ohp = oh & 1, owp = ow & 1;

    float a0 = bv.x, a1 = bv.y, a2 = bv.z, a3 = bv.w;
#pragma unroll
    for (int th = 0; th < 2; ++th) {
      int kh = th * 2 + ohp;
      int ih = (oh + kh - 2) >> 1;
      bool okh = (unsigned)ih < 64u;
#pragma unroll
      for (int tw = 0; tw < 2; ++tw) {
        int kw = tw * 2 + owp;
        int iw = (ow + kw - 2) >> 1;
        bool ok = okh && ((unsigned)iw < 64u);
        if (ok) {
          float4 v = *(const float4*)(hb + (ih * 64 + iw) * 4);
          int k16 = (kh * 4 + kw) * 16;
          float4 w0 = s_w4[k16 + 0 * 4 + cb];
          float4 w1 = s_w4[k16 + 1 * 4 + cb];
          float4 w2 = s_w4[k16 + 2 * 4 + cb];
          float4 w3 = s_w4[k16 + 3 * 4 + cb];
          a0 = fmaf(v.x, w0.x, fmaf(v.y, w1.x, fmaf(v.z, w2.x, fmaf(v.w, w3.x, a0))));
          a1 = fmaf(v.x, w0.y, fmaf(v.y, w1.y, fmaf(v.z, w2.y, fmaf(v.w, w3.y, a1))));
          a2 = fmaf(v.x, w0.z, fmaf(v.y, w1.z, fmaf(v.z, w2.z, fmaf(v.w, w3.z, a2))));
          a3 = fmaf(v.x, w0.w, fmaf(v.y, w1.w, fmaf(v.z, w2.w, fmaf(v.w, w3.w, a3))));
        }
      }
    }
    *(float4*)(h4 + (size_t)pos * 16 + cb * 4) = make_float4(a0, a1, a2, a3);
    lsum[0] += a0; lsum[1] += a1; lsum[2] += a2; lsum[3] += a3;
    lsq[0] = fmaf(a0, a0, lsq[0]); lsq[1] = fmaf(a1, a1, lsq[1]);
    lsq[2] = fmaf(a2, a2, lsq[2]); lsq[3] = fmaf(a3, a3, lsq[3]);
  }

#pragma unroll
  for (int j = 0; j < 4; ++j) {
    float sv = lsum[j], qv = lsq[j];
#pragma unroll
    for (int d = 4; d < 64; d <<= 1) { sv += __shfl_down(sv, d); qv += __shfl_down(qv, d); }
    if (lane < 4) {
      part[(lane * 4 + j) * 4096 + gwave]      = sv;
      part[(16 + lane * 4 + j) * 4096 + gwave] = qv;
    }
  }
}

// ---------------- K9: convT2 (16->1), LDS-tiled, XCD-swizzled --------------
__global__ __launch_bounds__(256) void k_convt2(
    const float* __restrict__ h4, const float* __restrict__ w,
    const float* __restrict__ bias, const float* __restrict__ bnp,
    float* __restrict__ out)
{
  __shared__ float4 s_t[4][18][19];
  __shared__ float s_w[256];     // [ci16][kh4][kw4]
  const int tid = threadIdx.x;
  s_w[tid] = w[tid];

  // bijective XCD swizzle: grid 4096 = 8 * 512
  const int bx = ((blockIdx.x & 7) << 9) | (blockIdx.x >> 3);
  const int n = bx >> 6;
  const int tile = bx & 63;
  const int ta = ((tile >> 3) << 4);   // input tile origin row
  const int tb = ((tile & 7) << 4);    // input tile origin col
  const float* hb = h4 + (size_t)n * 262144;

  for (int i = tid; i < 1296; i += 256) {     // 324 positions x 4 groups
    int g = i & 3, p = i >> 2;
    int row = p / 18, col = p - row * 18;
    int ih = ta - 1 + row, iw = tb - 1 + col;
    float4 t = make_float4(0.f, 0.f, 0.f, 0.f);
    if (((unsigned)ih < 128u) && ((unsigned)iw < 128u)) {
      float4 v   = *(const float4*)(hb + ((ih << 7) + iw) * 16 + (g << 2));
      float4 scv = *(const float4*)(bnp + 40 + (g << 2));
      float4 shv = *(const float4*)(bnp + 56 + (g << 2));
      t.x = fmaxf(fmaf(v.x, scv.x, shv.x), 0.f);
      t.y = fmaxf(fmaf(v.y, scv.y, shv.y), 0.f);
      t.z = fmaxf(fmaf(v.z, scv.z, shv.z), 0.f);
      t.w = fmaxf(fmaf(v.w, scv.w, shv.w), 0.f);
    }
    s_t[g][row][col] = t;
  }
  __syncthreads();

  const int a = tid >> 4, b = tid & 15;
  const float4* s_w4 = (const float4*)s_w;
  float acc00 = 0.f, acc01 = 0.f, acc10 = 0.f, acc11 = 0.f;

#pragma unroll
  for (int g = 0; g < 4; ++g) {
    float4 v00 = s_t[g][a  ][b  ], v01 = s_t[g][a  ][b+1], v02 = s_t[g][a  ][b+2];
    float4 v10 = s_t[g][a+1][b  ], v11 = s_t[g][a+1][b+1], v12 = s_t[g][a+1][b+2];
    float4 v20 = s_t[g][a+2][b  ], v21 = s_t[g][a+2][b+1], v22 = s_t[g][a+2][b+2];
#pragma unroll
    for (int j = 0; j < 4; ++j) {
      int ci = g * 4 + j;
      float4 r0 = s_w4[ci*4+0], r1 = s_w4[ci*4+1];
      float4 r2 = s_w4[ci*4+2], r3 = s_w4[ci*4+3];
      float a00 = (j==0)?v00.x:(j==1)?v00.y:(j==2)?v00.z:v00.w;
      float a01 = (j==0)?v01.x:(j==1)?v01.y:(j==2)?v01.z:v01.w;
      float a02 = (j==0)?v02.x:(j==1)?v02.y:(j==2)?v02.z:v02.w;
      float a10 = (j==0)?v10.x:(j==1)?v10.y:(j==2)?v10.z:v10.w;
      float a11 = (j==0)?v11.x:(j==1)?v11.y:(j==2)?v11.z:v11.w;
      float a12 = (j==0)?v12.x:(j==1)?v12.y:(j==2)?v12.z:v12.w;
      float a20 = (j==0)?v20.x:(j==1)?v20.y:(j==2)?v20.z:v20.w;
      float a21 = (j==0)?v21.x:(j==1)?v21.y:(j==2)?v21.z:v21.w;
      float a22 = (j==0)?v22.x:(j==1)?v22.y:(j==2)?v22.z:v22.w;
      acc00 += a00*r0.x + a01*r0.z + a10*r2.x + a11*r2.z;
      acc01 += a01*r0.y + a02*r0.w + a11*r2.y + a12*r2.w;
      acc10 += a10*r1.x + a11*r1.z + a20*r3.x + a21*r3.z;
      acc11 += a11*r1.y + a12*r1.w + a21*r3.y + a22*r3.w;
    }
  }
  const float bv = bias[0];
  const int A = ta + a, B = tb + b;
  float* ob = out + n * 65536 + (2 * A) * 256 + 2 * B;
  *(float2*)ob         = make_float2(acc00 + bv, acc01 + bv);
  *(float2*)(ob + 256) = make_float2(acc10 + bv, acc11 + bv);
}

// ---------------------------------------------------------------------------
extern "C" void kernel_launch(void* const* d_in, const int* in_sizes, int n_in,
                              void* d_out, int out_size, void* d_ws, size_t ws_size,
                              hipStream_t stream)
{
  const float* x      = (const float*)d_in[0];
  const float* enc_w1 = (const float*)d_in[1];
  const float* enc_b1 = (const float*)d_in[2];
  const float* bn1_g  = (const float*)d_in[3];
  const float* bn1_b  = (const float*)d_in[4];
  const float* enc_w2 = (const float*)d_in[5];
  const float* enc_b2 = (const float*)d_in[6];
  const float* bn2_g  = (const float*)d_in[7];
  const float* bn2_b  = (const float*)d_in[8];
  const float* pre_w  = (const float*)d_in[9];
  const float* pre_b  = (const float*)d_in[10];
  const float* cb     = (const float*)d_in[11];
  const float* post_w = (const float*)d_in[12];
  const float* post_b = (const float*)d_in[13];
  const float* dec_w1 = (const float*)d_in[14];
  const float* dec_b1 = (const float*)d_in[15];
  const float* bn3_g  = (const float*)d_in[16];
  const float* bn3_b  = (const float*)d_in[17];
  const float* dec_w2 = (const float*)d_in[18];
  const float* dec_b2 = (const float*)d_in[19];

  float* ws  = (float*)d_ws;
  float* y1  = ws;                       // 16,777,216 f (NHWC) -- reused as h4
  float* y2  = ws + 16777216;            //  1,048,576 f
  float* h3  = ws + 17825792;            //  1,048,576 f
  float* p1  = ws + 18874368;            //    131,072 f ([32][4096]) -- also p3
  float* p2  = ws + 19005440;            //      8,192 f ([1024][8])
  float* lp  = ws + 19013632;            //      1,024 f
  float* bnp = ws + 19014656;            //         72 f (sc1,sh1,sc2,sh2,sc3,sh3)
  float* h4  = y1;
  float* p3  = p1;
  float* out = (float*)d_out;

  k_conv1<<<1024, 256, 0, stream>>>(x, enc_w1, enc_b1, y1, p1);
  k_bnred16<<<16, 256, 0, stream>>>(p1, bn1_g, bn1_b, bnp, bnp + 16, 1.0 / 1048576.0);
  k_conv2<<<1024, 256, 0, stream>>>(y1, enc_w2, enc_b2, bnp, y2, p2);
  k_bnred4<<<1, 256, 0, stream>>>(p2, bn2_g, bn2_b, bnp + 32, bnp + 36, 1.0 / 262144.0);
  k_vq<<<1024, 256, 0, stream>>>(y2, bnp + 32, pre_w, pre_b, cb, post_w, post_b, h3, lp);
  k_lossfin<<<1, 256, 0, stream>>>(lp, out + 4194304);
  k_convt1<<<1024, 256, 0, stream>>>(h3, dec_w1, dec_b1, h4, p3);
  k_bnred16<<<16, 256, 0, stream>>>(p3, bn3_g, bn3_b, bnp + 40, bnp + 56, 1.0 / 1048576.0);
  k_convt2<<<4096, 256, 0, stream>>>(h4, dec_w2, dec_b2, bnp, out);
}

// Round 11
// 140.671 us; speedup vs baseline: 1.4325x; 1.0523x over previous
//
#include <hip/hip_runtime.h>

// ---------------------------------------------------------------------------
// VQ-VAE forward, f32, NHWC intermediates (channels innermost -> float4 I/O).
//  K1 conv1 (1->16) co-split (out-ch), 4096 blk P=4 -> y1 [64,128,128,16]
//  K2 bn1 reduce (16 blocks, transposed partials [stat32][16384])
//  K3 conv2 (16->4) co-split (IN-ch quad/lane), 4096 blk, 8 waves/SIMD,
//     guarded reads, bn1+relu on read, XCD-swizzled -> y2
//  K4 bn2 reduce (4 blocks)
//  K5 VQ fused -> h3
//  K6 loss finalize -> d_out[4194304]
//  K7 convT1 (4->16) co-split (out-ch), 4096 blk P=4 -> h4 (reuses y1)
//  K8 bn3 reduce (16 blocks)
//  K9 convT2 (16->1), LDS-tiled, XCD-swizzled -> d_out
// R10 lesson: conv2 was latency-bound at 4096 waves; input-channel co-split
// quadruples TLP at identical traffic/FLOPs.
// ---------------------------------------------------------------------------

// ---------------- K1: conv1 co-split + per-channel stats -------------------
__global__ __launch_bounds__(256) void k_conv1(
    const float* __restrict__ x, const float* __restrict__ w1,
    const float* __restrict__ b1, float* __restrict__ y1,
    float* __restrict__ part)
{
  __shared__ float s_w[256];     // [k16][c16]
  __shared__ float s_b[16];
  const int tid = threadIdx.x;
  { int c = tid >> 4, k = tid & 15; s_w[k * 16 + c] = w1[c * 16 + k]; }
  if (tid < 16) s_b[tid] = b1[tid];
  __syncthreads();

  const int lane = tid & 63;
  const int cb = lane & 3;                  // out-channel quad
  const int psl = lane >> 2;                // pixel slot 0..15
  const int gwave = (blockIdx.x << 2) | (tid >> 6);   // 16384 waves
  const int base = gwave << 6;              // 64 pixels per wave
  const int n = base >> 14;
  const float* xb = x + n * 65536;
  const float4* s_w4 = (const float4*)s_w;
  const float4 bv = ((const float4*)s_b)[cb];

  float lsum[4] = {0.f, 0.f, 0.f, 0.f}, lsq[4] = {0.f, 0.f, 0.f, 0.f};

#pragma unroll 1
  for (int i = 0; i < 4; ++i) {
    const int pos = base + (i << 4) + psl;
    const int r = pos & 16383;
    const int oh = r >> 7, ow = r & 127;
    const int ihb = oh * 2 - 1, iwb = ow * 2 - 1;

    float a0 = bv.x, a1 = bv.y, a2 = bv.z, a3 = bv.w;
#pragma unroll
    for (int kh = 0; kh < 4; ++kh) {
      int ih = ihb + kh; bool okh = (unsigned)ih < 256u;
#pragma unroll
      for (int kw = 0; kw < 4; ++kw) {
        int iw = iwb + kw;
        bool ok = okh && ((unsigned)iw < 256u);
        float v = ok ? xb[ih * 256 + iw] : 0.f;
        float4 wv = s_w4[(kh * 4 + kw) * 4 + cb];
        a0 = fmaf(v, wv.x, a0); a1 = fmaf(v, wv.y, a1);
        a2 = fmaf(v, wv.z, a2); a3 = fmaf(v, wv.w, a3);
      }
    }
    *(float4*)(y1 + (size_t)pos * 16 + cb * 4) = make_float4(a0, a1, a2, a3);
    lsum[0] += a0; lsum[1] += a1; lsum[2] += a2; lsum[3] += a3;
    lsq[0] = fmaf(a0, a0, lsq[0]); lsq[1] = fmaf(a1, a1, lsq[1]);
    lsq[2] = fmaf(a2, a2, lsq[2]); lsq[3] = fmaf(a3, a3, lsq[3]);
  }

  // transposed partials: part[stat 0..31][16384]
#pragma unroll
  for (int j = 0; j < 4; ++j) {
    float sv = lsum[j], qv = lsq[j];
#pragma unroll
    for (int d = 4; d < 64; d <<= 1) { sv += __shfl_down(sv, d); qv += __shfl_down(qv, d); }
    if (lane < 4) {
      part[(lane * 4 + j) * 16384 + gwave]      = sv;
      part[(16 + lane * 4 + j) * 16384 + gwave] = qv;
    }
  }
}

// ---------------- BN reduce: NCH blocks, NW per-wave partials --------------
template <int NCH, int NW>
__global__ __launch_bounds__(256) void k_bnredN(
    const float* __restrict__ part, const float* __restrict__ g,
    const float* __restrict__ bt, float* __restrict__ sc,
    float* __restrict__ sh, double invN)
{
  __shared__ double sd[256], sqd[256];
  const int c = blockIdx.x, tid = threadIdx.x;
  const float4* ps = (const float4*)(part + (size_t)c * NW);
  const float4* pq = (const float4*)(part + (size_t)(NCH + c) * NW);
  double S = 0.0, Q = 0.0;
#pragma unroll
  for (int i = 0; i < NW / 1024; ++i) {
    float4 v = ps[i * 256 + tid];
    S += (double)v.x + (double)v.y + (double)v.z + (double)v.w;
    float4 q = pq[i * 256 + tid];
    Q += (double)q.x + (double)q.y + (double)q.z + (double)q.w;
  }
  sd[tid] = S; sqd[tid] = Q;
  __syncthreads();
  for (int off = 128; off > 0; off >>= 1) {
    if (tid < off) { sd[tid] += sd[tid + off]; sqd[tid] += sqd[tid + off]; }
    __syncthreads();
  }
  if (tid == 0) {
    double mean = sd[0] * invN;
    double var  = sqd[0] * invN - mean * mean;
    float scale = (float)((double)g[c] / sqrt(var + 1e-5));
    sc[c] = scale;
    sh[c] = bt[c] - (float)mean * scale;
  }
}

// ---------------- K3: conv2 co-split over INPUT channels -------------------
// 4 lanes/output-pixel; lane cb handles ci quad cb (16 taps x 1 float4 load).
// Quad shfl_xor reduce -> bias -> cb==0 stores. 16384 waves = 8/SIMD.
__global__ __launch_bounds__(256) void k_conv2(
    const float* __restrict__ y1, const float* __restrict__ w2,
    const float* __restrict__ b2, const float* __restrict__ bnp,
    float* __restrict__ y2, float* __restrict__ part)
{
  __shared__ float s_w[1024];        // [k16][ci16][co4]
  __shared__ float s_sc[16], s_sh[16];
  __shared__ float s_b[4];
  const int tid = threadIdx.x;
  for (int i = tid; i < 1024; i += 256) {
    int co = i & 3, ci = (i >> 2) & 15, k = i >> 6;
    int kh = k >> 2, kw = k & 3;
    s_w[i] = w2[((co * 16 + ci) * 4 + kh) * 4 + kw];
  }
  if (tid < 16) { s_sc[tid] = bnp[tid]; s_sh[tid] = bnp[16 + tid]; }
  if (tid < 4)  s_b[tid] = b2[tid];
  __syncthreads();

  // bijective XCD swizzle: grid 4096 = 8 * 512
  const int bid = ((blockIdx.x & 7) << 9) | (blockIdx.x >> 3);
  const int lane = tid & 63;
  const int cb = lane & 3;                 // input-channel quad
  const int psl = lane >> 2;               // pixel slot 0..15
  const int gwave = (bid << 2) | (tid >> 6);   // 16384 waves
  const int pos = (gwave << 4) + psl;          // < 262,144
  const int n = pos >> 12, r = pos & 4095;
  const int oh = r >> 6, ow = r & 63;
  const int ihb = oh * 2 - 1, iwb = ow * 2 - 1;
  const float* yb = y1 + (size_t)n * 262144;
  const float4* s_w4 = (const float4*)s_w;
  const float4 scv = ((const float4*)s_sc)[cb];
  const float4 shv = ((const float4*)s_sh)[cb];

  float acc0 = 0.f, acc1 = 0.f, acc2 = 0.f, acc3 = 0.f;

#pragma unroll
  for (int kh = 0; kh < 4; ++kh) {
    int ih = ihb + kh; bool okh = (unsigned)ih < 128u;
#pragma unroll
    for (int kw = 0; kw < 4; ++kw) {
      int iw = iwb + kw;
      bool ok = okh && ((unsigned)iw < 128u);
      if (ok) {
        float4 v = *(const float4*)(yb + (ih * 128 + iw) * 16 + (cb << 2));
        float a0 = fmaxf(fmaf(v.x, scv.x, shv.x), 0.f);
        float a1 = fmaxf(fmaf(v.y, scv.y, shv.y), 0.f);
        float a2 = fmaxf(fmaf(v.z, scv.z, shv.z), 0.f);
        float a3 = fmaxf(fmaf(v.w, scv.w, shv.w), 0.f);
        int kb = (((kh << 2) | kw) << 4) + (cb << 2);
        float4 w0 = s_w4[kb + 0];
        float4 w1 = s_w4[kb + 1];
        float4 w2v = s_w4[kb + 2];
        float4 w3 = s_w4[kb + 3];
        acc0 = fmaf(a0, w0.x, fmaf(a1, w1.x, fmaf(a2, w2v.x, fmaf(a3, w3.x, acc0))));
        acc1 = fmaf(a0, w0.y, fmaf(a1, w1.y, fmaf(a2, w2v.y, fmaf(a3, w3.y, acc1))));
        acc2 = fmaf(a0, w0.z, fmaf(a1, w1.z, fmaf(a2, w2v.z, fmaf(a3, w3.z, acc2))));
        acc3 = fmaf(a0, w0.w, fmaf(a1, w1.w, fmaf(a2, w2v.w, fmaf(a3, w3.w, acc3))));
      }
    }
  }
  // reduce over the 4 ci-quads (lanes of the quad)
  acc0 += __shfl_xor(acc0, 1); acc0 += __shfl_xor(acc0, 2);
  acc1 += __shfl_xor(acc1, 1); acc1 += __shfl_xor(acc1, 2);
  acc2 += __shfl_xor(acc2, 1); acc2 += __shfl_xor(acc2, 2);
  acc3 += __shfl_xor(acc3, 1); acc3 += __shfl_xor(acc3, 2);
  acc0 += s_b[0]; acc1 += s_b[1]; acc2 += s_b[2]; acc3 += s_b[3];

  if (cb == 0)
    *(float4*)(y2 + (size_t)pos * 4) = make_float4(acc0, acc1, acc2, acc3);

  // stats: quad-mates identical; strides 4..32 sum the 16 pixel slots once
  float ls[4] = {acc0, acc1, acc2, acc3};
#pragma unroll
  for (int c = 0; c < 4; ++c) {
    float sv = ls[c], qv = ls[c] * ls[c];
#pragma unroll
    for (int d = 4; d < 64; d <<= 1) { sv += __shfl_down(sv, d); qv += __shfl_down(qv, d); }
    if (lane == 0) {
      part[c * 16384 + gwave]       = sv;
      part[(4 + c) * 16384 + gwave] = qv;
    }
  }
}

// ---------------- K5: fused VQ -------------------------------------------
__global__ __launch_bounds__(256) void k_vq(
    const float* __restrict__ y2, const float* __restrict__ bnp2,
    const float* __restrict__ pw, const float* __restrict__ pb,
    const float* __restrict__ cb, const float* __restrict__ postw,
    const float* __restrict__ postb, float* __restrict__ h3,
    float* __restrict__ lpart)
{
  const int tid = threadIdx.x;
  const int pos = blockIdx.x * 256 + tid;     // < 262,144
  float4 v = *(const float4*)(y2 + (size_t)pos * 4);
  float aa0 = fmaxf(fmaf(v.x, bnp2[0], bnp2[4]), 0.f);
  float aa1 = fmaxf(fmaf(v.y, bnp2[1], bnp2[5]), 0.f);
  float aa2 = fmaxf(fmaf(v.z, bnp2[2], bnp2[6]), 0.f);
  float aa3 = fmaxf(fmaf(v.w, bnp2[3], bnp2[7]), 0.f);
  float z0 = pb[0] + aa0*pw[0] + aa1*pw[1] + aa2*pw[2] + aa3*pw[3];
  float z1 = pb[1] + aa0*pw[4] + aa1*pw[5] + aa2*pw[6] + aa3*pw[7];

  float best = 3.4e38f, q0 = 0.f, q1 = 0.f;
#pragma unroll
  for (int k = 0; k < 3; ++k) {
    float c0 = cb[2 * k], c1 = cb[2 * k + 1];
    float dx = z0 - c0, dy = z1 - c1;
    float d = dx * dx + dy * dy;
    if (d < best) { best = d; q0 = c0; q1 = c1; }   // strict < == first-min
  }
  float dl = (q0 - z0) * (q0 - z0) + (q1 - z1) * (q1 - z1);

  float4 hv;
  hv.x = fmaf(q0, postw[0], fmaf(q1, postw[1], postb[0]));
  hv.y = fmaf(q0, postw[2], fmaf(q1, postw[3], postb[1]));
  hv.z = fmaf(q0, postw[4], fmaf(q1, postw[5], postb[2]));
  hv.w = fmaf(q0, postw[6], fmaf(q1, postw[7], postb[3]));
  *(float4*)(h3 + (size_t)pos * 4) = hv;

  float s = dl;
#pragma unroll
  for (int d = 32; d > 0; d >>= 1) s += __shfl_down(s, d);
  __shared__ float ws4[4];
  if ((tid & 63) == 0) ws4[tid >> 6] = s;
  __syncthreads();
  if (tid == 0) lpart[blockIdx.x] = (ws4[0] + ws4[1]) + (ws4[2] + ws4[3]);
}

__global__ __launch_bounds__(256) void k_lossfin(
    const float* __restrict__ lpart, float* __restrict__ outp)
{
  const int tid = threadIdx.x;
  float s = lpart[tid] + lpart[tid + 256] + lpart[tid + 512] + lpart[tid + 768];
#pragma unroll
  for (int d = 32; d > 0; d >>= 1) s += __shfl_down(s, d);
  __shared__ float ws4[4];
  if ((tid & 63) == 0) ws4[tid >> 6] = s;
  __syncthreads();
  if (tid == 0) {
    double tot = (double)ws4[0] + (double)ws4[1] + (double)ws4[2] + (double)ws4[3];
    outp[0] = (float)(1.2 * tot / 524288.0);   // (1+BETA) * mean over B*N*C
  }
}

// ---------------- K7: convT1 (4->16) co-split + stats ----------------------
__global__ __launch_bounds__(256) void k_convt1(
    const float* __restrict__ h3, const float* __restrict__ w,
    const float* __restrict__ bias, float* __restrict__ h4,
    float* __restrict__ part)
{
  __shared__ float s_w[1024];   // [k16][ci4][co16]
  __shared__ float s_b[16];
  const int tid = threadIdx.x;
  for (int i = tid; i < 1024; i += 256) {
    int co = i & 15, ci = (i >> 4) & 3, k = i >> 6;
    int kh = k >> 2, kw = k & 3;
    s_w[i] = w[((co * 4 + ci) * 4 + kh) * 4 + kw];
  }
  if (tid < 16) s_b[tid] = bias[tid];
  __syncthreads();

  const int lane = tid & 63;
  const int cb = lane & 3;
  const int psl = lane >> 2;
  const int gwave = (blockIdx.x << 2) | (tid >> 6);   // 16384 waves
  const int base = gwave << 6;              // 64 pixels per wave
  const int n = base >> 14;
  const float* hb = h3 + (size_t)n * 16384;
  const float4* s_w4 = (const float4*)s_w;   // idx = k*16 + ci*4 + cb
  const float4 bv = ((const float4*)s_b)[cb];

  float lsum[4] = {0.f, 0.f, 0.f, 0.f}, lsq[4] = {0.f, 0.f, 0.f, 0.f};

#pragma unroll 1
  for (int i = 0; i < 4; ++i) {
    const int pos = base + (i << 4) + psl;
    const int r = pos & 16383;
    const int oh = r >> 7, ow = r & 127;
    const int ohp = oh & 1, owp = ow & 1;

    float a0 = bv.x, a1 = bv.y, a2 = bv.z, a3 = bv.w;
#pragma unroll
    for (int th = 0; th < 2; ++th) {
      int kh = th * 2 + ohp;
      int ih = (oh + kh - 2) >> 1;
      bool okh = (unsigned)ih < 64u;
#pragma unroll
      for (int tw = 0; tw < 2; ++tw) {
        int kw = tw * 2 + owp;
        int iw = (ow + kw - 2) >> 1;
        bool ok = okh && ((unsigned)iw < 64u);
        if (ok) {
          float4 v = *(const float4*)(hb + (ih * 64 + iw) * 4);
          int k16 = (kh * 4 + kw) * 16;
          float4 w0 = s_w4[k16 + 0 * 4 + cb];
          float4 w1 = s_w4[k16 + 1 * 4 + cb];
          float4 w2 = s_w4[k16 + 2 * 4 + cb];
          float4 w3 = s_w4[k16 + 3 * 4 + cb];
          a0 = fmaf(v.x, w0.x, fmaf(v.y, w1.x, fmaf(v.z, w2.x, fmaf(v.w, w3.x, a0))));
          a1 = fmaf(v.x, w0.y, fmaf(v.y, w1.y, fmaf(v.z, w2.y, fmaf(v.w, w3.y, a1))));
          a2 = fmaf(v.x, w0.z, fmaf(v.y, w1.z, fmaf(v.z, w2.z, fmaf(v.w, w3.z, a2))));
          a3 = fmaf(v.x, w0.w, fmaf(v.y, w1.w, fmaf(v.z, w2.w, fmaf(v.w, w3.w, a3))));
        }
      }
    }
    *(float4*)(h4 + (size_t)pos * 16 + cb * 4) = make_float4(a0, a1, a2, a3);
    lsum[0] += a0; lsum[1] += a1; lsum[2] += a2; lsum[3] += a3;
    lsq[0] = fmaf(a0, a0, lsq[0]); lsq[1] = fmaf(a1, a1, lsq[1]);
    lsq[2] = fmaf(a2, a2, lsq[2]); lsq[3] = fmaf(a3, a3, lsq[3]);
  }

#pragma unroll
  for (int j = 0; j < 4; ++j) {
    float sv = lsum[j], qv = lsq[j];
#pragma unroll
    for (int d = 4; d < 64; d <<= 1) { sv += __shfl_down(sv, d); qv += __shfl_down(qv, d); }
    if (lane < 4) {
      part[(lane * 4 + j) * 16384 + gwave]      = sv;
      part[(16 + lane * 4 + j) * 16384 + gwave] = qv;
    }
  }
}

// ---------------- K9: convT2 (16->1), LDS-tiled, XCD-swizzled --------------
__global__ __launch_bounds__(256) void k_convt2(
    const float* __restrict__ h4, const float* __restrict__ w,
    const float* __restrict__ bias, const float* __restrict__ bnp,
    float* __restrict__ out)
{
  __shared__ float4 s_t[4][18][19];
  __shared__ float s_w[256];     // [ci16][kh4][kw4]
  const int tid = threadIdx.x;
  s_w[tid] = w[tid];

  // bijective XCD swizzle: grid 4096 = 8 * 512
  const int bx = ((blockIdx.x & 7) << 9) | (blockIdx.x >> 3);
  const int n = bx >> 6;
  const int tile = bx & 63;
  const int ta = ((tile >> 3) << 4);   // input tile origin row
  const int tb = ((tile & 7) << 4);    // input tile origin col
  const float* hb = h4 + (size_t)n * 262144;

  for (int i = tid; i < 1296; i += 256) {     // 324 positions x 4 groups
    int g = i & 3, p = i >> 2;
    int row = p / 18, col = p - row * 18;
    int ih = ta - 1 + row, iw = tb - 1 + col;
    float4 t = make_float4(0.f, 0.f, 0.f, 0.f);
    if (((unsigned)ih < 128u) && ((unsigned)iw < 128u)) {
      float4 v   = *(const float4*)(hb + ((ih << 7) + iw) * 16 + (g << 2));
      float4 scv = *(const float4*)(bnp + 40 + (g << 2));
      float4 shv = *(const float4*)(bnp + 56 + (g << 2));
      t.x = fmaxf(fmaf(v.x, scv.x, shv.x), 0.f);
      t.y = fmaxf(fmaf(v.y, scv.y, shv.y), 0.f);
      t.z = fmaxf(fmaf(v.z, scv.z, shv.z), 0.f);
      t.w = fmaxf(fmaf(v.w, scv.w, shv.w), 0.f);
    }
    s_t[g][row][col] = t;
  }
  __syncthreads();

  const int a = tid >> 4, b = tid & 15;
  const float4* s_w4 = (const float4*)s_w;
  float acc00 = 0.f, acc01 = 0.f, acc10 = 0.f, acc11 = 0.f;

#pragma unroll
  for (int g = 0; g < 4; ++g) {
    float4 v00 = s_t[g][a  ][b  ], v01 = s_t[g][a  ][b+1], v02 = s_t[g][a  ][b+2];
    float4 v10 = s_t[g][a+1][b  ], v11 = s_t[g][a+1][b+1], v12 = s_t[g][a+1][b+2];
    float4 v20 = s_t[g][a+2][b  ], v21 = s_t[g][a+2][b+1], v22 = s_t[g][a+2][b+2];
#pragma unroll
    for (int j = 0; j < 4; ++j) {
      int ci = g * 4 + j;
      float4 r0 = s_w4[ci*4+0], r1 = s_w4[ci*4+1];
      float4 r2 = s_w4[ci*4+2], r3 = s_w4[ci*4+3];
      float a00 = (j==0)?v00.x:(j==1)?v00.y:(j==2)?v00.z:v00.w;
      float a01 = (j==0)?v01.x:(j==1)?v01.y:(j==2)?v01.z:v01.w;
      float a02 = (j==0)?v02.x:(j==1)?v02.y:(j==2)?v02.z:v02.w;
      float a10 = (j==0)?v10.x:(j==1)?v10.y:(j==2)?v10.z:v10.w;
      float a11 = (j==0)?v11.x:(j==1)?v11.y:(j==2)?v11.z:v11.w;
      float a12 = (j==0)?v12.x:(j==1)?v12.y:(j==2)?v12.z:v12.w;
      float a20 = (j==0)?v20.x:(j==1)?v20.y:(j==2)?v20.z:v20.w;
      float a21 = (j==0)?v21.x:(j==1)?v21.y:(j==2)?v21.z:v21.w;
      float a22 = (j==0)?v22.x:(j==1)?v22.y:(j==2)?v22.z:v22.w;
      acc00 += a00*r0.x + a01*r0.z + a10*r2.x + a11*r2.z;
      acc01 += a01*r0.y + a02*r0.w + a11*r2.y + a12*r2.w;
      acc10 += a10*r1.x + a11*r1.z + a20*r3.x + a21*r3.z;
      acc11 += a11*r1.y + a12*r1.w + a21*r3.y + a22*r3.w;
    }
  }
  const float bv = bias[0];
  const int A = ta + a, B = tb + b;
  float* ob = out + n * 65536 + (2 * A) * 256 + 2 * B;
  *(float2*)ob         = make_float2(acc00 + bv, acc01 + bv);
  *(float2*)(ob + 256) = make_float2(acc10 + bv, acc11 + bv);
}

// ---------------------------------------------------------------------------
extern "C" void kernel_launch(void* const* d_in, const int* in_sizes, int n_in,
                              void* d_out, int out_size, void* d_ws, size_t ws_size,
                              hipStream_t stream)
{
  const float* x      = (const float*)d_in[0];
  const float* enc_w1 = (const float*)d_in[1];
  const float* enc_b1 = (const float*)d_in[2];
  const float* bn1_g  = (const float*)d_in[3];
  const float* bn1_b  = (const float*)d_in[4];
  const float* enc_w2 = (const float*)d_in[5];
  const float* enc_b2 = (const float*)d_in[6];
  const float* bn2_g  = (const float*)d_in[7];
  const float* bn2_b  = (const float*)d_in[8];
  const float* pre_w  = (const float*)d_in[9];
  const float* pre_b  = (const float*)d_in[10];
  const float* cb     = (const float*)d_in[11];
  const float* post_w = (const float*)d_in[12];
  const float* post_b = (const float*)d_in[13];
  const float* dec_w1 = (const float*)d_in[14];
  const float* dec_b1 = (const float*)d_in[15];
  const float* bn3_g  = (const float*)d_in[16];
  const float* bn3_b  = (const float*)d_in[17];
  const float* dec_w2 = (const float*)d_in[18];
  const float* dec_b2 = (const float*)d_in[19];

  float* ws  = (float*)d_ws;
  float* y1  = ws;                       // 16,777,216 f (NHWC) -- reused as h4
  float* y2  = ws + 16777216;            //  1,048,576 f
  float* h3  = ws + 17825792;            //  1,048,576 f
  float* p1  = ws + 18874368;            //    524,288 f ([32][16384]) -- also p3
  float* p2  = ws + 19398656;            //    131,072 f ([8][16384])
  float* lp  = ws + 19529728;            //      1,024 f
  float* bnp = ws + 19530752;            //         72 f (sc1,sh1,sc2,sh2,sc3,sh3)
  float* h4  = y1;
  float* p3  = p1;
  float* out = (float*)d_out;

  k_conv1<<<4096, 256, 0, stream>>>(x, enc_w1, enc_b1, y1, p1);
  k_bnredN<16, 16384><<<16, 256, 0, stream>>>(p1, bn1_g, bn1_b, bnp, bnp + 16, 1.0 / 1048576.0);
  k_conv2<<<4096, 256, 0, stream>>>(y1, enc_w2, enc_b2, bnp, y2, p2);
  k_bnredN<4, 16384><<<4, 256, 0, stream>>>(p2, bn2_g, bn2_b, bnp + 32, bnp + 36, 1.0 / 262144.0);
  k_vq<<<1024, 256, 0, stream>>>(y2, bnp + 32, pre_w, pre_b, cb, post_w, post_b, h3, lp);
  k_lossfin<<<1, 256, 0, stream>>>(lp, out + 4194304);
  k_convt1<<<4096, 256, 0, stream>>>(h3, dec_w1, dec_b1, h4, p3);
  k_bnredN<16, 16384><<<16, 256, 0, stream>>>(p3, bn3_g, bn3_b, bnp + 40, bnp + 56, 1.0 / 1048576.0);
  k_convt2<<<4096, 256, 0, stream>>>(h4, dec_w2, dec_b2, bnp, out);
}

// Round 12
// 135.191 us; speedup vs baseline: 1.4905x; 1.0405x over previous
//
#include <hip/hip_runtime.h>

// ---------------------------------------------------------------------------
// VQ-VAE forward, f32, NHWC intermediates (channels innermost -> float4 I/O).
//  K1 conv1 (1->16) co-split (out-ch), 1024 blk P=16 -> y1 [64,128,128,16]
//  K2 bn1 reduce (16 blocks, partials [stat32][4096])
//  K3 conv2 (16->4) co-split (IN-ch quad/lane), 4096 blk, 8 waves/SIMD,
//     guarded reads, bn1+relu on read, XCD-swizzled -> y2   [R11-proven]
//  K4 bn2 reduce (4 blocks, partials [8][16384])
//  K5 VQ fused -> h3
//  K6 loss finalize -> d_out[4194304]
//  K7 convT1 (4->16) co-split (out-ch), 1024 blk P=16 -> h4 (reuses y1)
//  K8 bn3 reduce (16 blocks)
//  K9 convT2 (16->1), LDS-tiled, XCD-swizzled -> d_out
// R11 lesson: changing conv1/convt1 to P=4 alongside conv2's co-split masked
// an ~18us regression (4x stats-tail executions). P=16 restored here.
// ---------------------------------------------------------------------------

// ---------------- K1: conv1 co-split + per-channel stats (P=16) ------------
__global__ __launch_bounds__(256) void k_conv1(
    const float* __restrict__ x, const float* __restrict__ w1,
    const float* __restrict__ b1, float* __restrict__ y1,
    float* __restrict__ part)
{
  __shared__ float s_w[256];     // [k16][c16]
  __shared__ float s_b[16];
  const int tid = threadIdx.x;
  { int c = tid >> 4, k = tid & 15; s_w[k * 16 + c] = w1[c * 16 + k]; }
  if (tid < 16) s_b[tid] = b1[tid];
  __syncthreads();

  const int lane = tid & 63;
  const int cb = lane & 3;                  // out-channel quad
  const int psl = lane >> 2;                // pixel slot 0..15
  const int gwave = (blockIdx.x << 2) | (tid >> 6);   // 4096 waves
  const int base = gwave << 8;              // 256 pixels per wave
  const int n = base >> 14;
  const float* xb = x + n * 65536;
  const float4* s_w4 = (const float4*)s_w;
  const float4 bv = ((const float4*)s_b)[cb];

  float lsum[4] = {0.f, 0.f, 0.f, 0.f}, lsq[4] = {0.f, 0.f, 0.f, 0.f};

#pragma unroll 1
  for (int i = 0; i < 16; ++i) {
    const int pos = base + (i << 4) + psl;
    const int r = pos & 16383;
    const int oh = r >> 7, ow = r & 127;
    const int ihb = oh * 2 - 1, iwb = ow * 2 - 1;

    float a0 = bv.x, a1 = bv.y, a2 = bv.z, a3 = bv.w;
#pragma unroll
    for (int kh = 0; kh < 4; ++kh) {
      int ih = ihb + kh; bool okh = (unsigned)ih < 256u;
#pragma unroll
      for (int kw = 0; kw < 4; ++kw) {
        int iw = iwb + kw;
        bool ok = okh && ((unsigned)iw < 256u);
        float v = ok ? xb[ih * 256 + iw] : 0.f;
        float4 wv = s_w4[(kh * 4 + kw) * 4 + cb];
        a0 = fmaf(v, wv.x, a0); a1 = fmaf(v, wv.y, a1);
        a2 = fmaf(v, wv.z, a2); a3 = fmaf(v, wv.w, a3);
      }
    }
    *(float4*)(y1 + (size_t)pos * 16 + cb * 4) = make_float4(a0, a1, a2, a3);
    lsum[0] += a0; lsum[1] += a1; lsum[2] += a2; lsum[3] += a3;
    lsq[0] = fmaf(a0, a0, lsq[0]); lsq[1] = fmaf(a1, a1, lsq[1]);
    lsq[2] = fmaf(a2, a2, lsq[2]); lsq[3] = fmaf(a3, a3, lsq[3]);
  }

  // transposed partials: part[stat 0..31][4096]
#pragma unroll
  for (int j = 0; j < 4; ++j) {
    float sv = lsum[j], qv = lsq[j];
#pragma unroll
    for (int d = 4; d < 64; d <<= 1) { sv += __shfl_down(sv, d); qv += __shfl_down(qv, d); }
    if (lane < 4) {
      part[(lane * 4 + j) * 4096 + gwave]      = sv;
      part[(16 + lane * 4 + j) * 4096 + gwave] = qv;
    }
  }
}

// ---------------- BN reduce: NCH blocks, NW per-wave partials --------------
template <int NCH, int NW>
__global__ __launch_bounds__(256) void k_bnredN(
    const float* __restrict__ part, const float* __restrict__ g,
    const float* __restrict__ bt, float* __restrict__ sc,
    float* __restrict__ sh, double invN)
{
  __shared__ double sd[256], sqd[256];
  const int c = blockIdx.x, tid = threadIdx.x;
  const float4* ps = (const float4*)(part + (size_t)c * NW);
  const float4* pq = (const float4*)(part + (size_t)(NCH + c) * NW);
  double S = 0.0, Q = 0.0;
#pragma unroll
  for (int i = 0; i < NW / 1024; ++i) {
    float4 v = ps[i * 256 + tid];
    S += (double)v.x + (double)v.y + (double)v.z + (double)v.w;
    float4 q = pq[i * 256 + tid];
    Q += (double)q.x + (double)q.y + (double)q.z + (double)q.w;
  }
  sd[tid] = S; sqd[tid] = Q;
  __syncthreads();
  for (int off = 128; off > 0; off >>= 1) {
    if (tid < off) { sd[tid] += sd[tid + off]; sqd[tid] += sqd[tid + off]; }
    __syncthreads();
  }
  if (tid == 0) {
    double mean = sd[0] * invN;
    double var  = sqd[0] * invN - mean * mean;
    float scale = (float)((double)g[c] / sqrt(var + 1e-5));
    sc[c] = scale;
    sh[c] = bt[c] - (float)mean * scale;
  }
}

// ---------------- K3: conv2 co-split over INPUT channels (R11-proven) ------
__global__ __launch_bounds__(256) void k_conv2(
    const float* __restrict__ y1, const float* __restrict__ w2,
    const float* __restrict__ b2, const float* __restrict__ bnp,
    float* __restrict__ y2, float* __restrict__ part)
{
  __shared__ float s_w[1024];        // [k16][ci16][co4]
  __shared__ float s_sc[16], s_sh[16];
  __shared__ float s_b[4];
  const int tid = threadIdx.x;
  for (int i = tid; i < 1024; i += 256) {
    int co = i & 3, ci = (i >> 2) & 15, k = i >> 6;
    int kh = k >> 2, kw = k & 3;
    s_w[i] = w2[((co * 16 + ci) * 4 + kh) * 4 + kw];
  }
  if (tid < 16) { s_sc[tid] = bnp[tid]; s_sh[tid] = bnp[16 + tid]; }
  if (tid < 4)  s_b[tid] = b2[tid];
  __syncthreads();

  // bijective XCD swizzle: grid 4096 = 8 * 512
  const int bid = ((blockIdx.x & 7) << 9) | (blockIdx.x >> 3);
  const int lane = tid & 63;
  const int cb = lane & 3;                 // input-channel quad
  const int psl = lane >> 2;               // pixel slot 0..15
  const int gwave = (bid << 2) | (tid >> 6);   // 16384 waves
  const int pos = (gwave << 4) + psl;          // < 262,144
  const int n = pos >> 12, r = pos & 4095;
  const int oh = r >> 6, ow = r & 63;
  const int ihb = oh * 2 - 1, iwb = ow * 2 - 1;
  const float* yb = y1 + (size_t)n * 262144;
  const float4* s_w4 = (const float4*)s_w;
  const float4 scv = ((const float4*)s_sc)[cb];
  const float4 shv = ((const float4*)s_sh)[cb];

  float acc0 = 0.f, acc1 = 0.f, acc2 = 0.f, acc3 = 0.f;

#pragma unroll
  for (int kh = 0; kh < 4; ++kh) {
    int ih = ihb + kh; bool okh = (unsigned)ih < 128u;
#pragma unroll
    for (int kw = 0; kw < 4; ++kw) {
      int iw = iwb + kw;
      bool ok = okh && ((unsigned)iw < 128u);
      if (ok) {
        float4 v = *(const float4*)(yb + (ih * 128 + iw) * 16 + (cb << 2));
        float a0 = fmaxf(fmaf(v.x, scv.x, shv.x), 0.f);
        float a1 = fmaxf(fmaf(v.y, scv.y, shv.y), 0.f);
        float a2 = fmaxf(fmaf(v.z, scv.z, shv.z), 0.f);
        float a3 = fmaxf(fmaf(v.w, scv.w, shv.w), 0.f);
        int kb = (((kh << 2) | kw) << 4) + (cb << 2);
        float4 w0 = s_w4[kb + 0];
        float4 w1 = s_w4[kb + 1];
        float4 w2v = s_w4[kb + 2];
        float4 w3 = s_w4[kb + 3];
        acc0 = fmaf(a0, w0.x, fmaf(a1, w1.x, fmaf(a2, w2v.x, fmaf(a3, w3.x, acc0))));
        acc1 = fmaf(a0, w0.y, fmaf(a1, w1.y, fmaf(a2, w2v.y, fmaf(a3, w3.y, acc1))));
        acc2 = fmaf(a0, w0.z, fmaf(a1, w1.z, fmaf(a2, w2v.z, fmaf(a3, w3.z, acc2))));
        acc3 = fmaf(a0, w0.w, fmaf(a1, w1.w, fmaf(a2, w2v.w, fmaf(a3, w3.w, acc3))));
      }
    }
  }
  // reduce over the 4 ci-quads
  acc0 += __shfl_xor(acc0, 1); acc0 += __shfl_xor(acc0, 2);
  acc1 += __shfl_xor(acc1, 1); acc1 += __shfl_xor(acc1, 2);
  acc2 += __shfl_xor(acc2, 1); acc2 += __shfl_xor(acc2, 2);
  acc3 += __shfl_xor(acc3, 1); acc3 += __shfl_xor(acc3, 2);
  acc0 += s_b[0]; acc1 += s_b[1]; acc2 += s_b[2]; acc3 += s_b[3];

  if (cb == 0)
    *(float4*)(y2 + (size_t)pos * 4) = make_float4(acc0, acc1, acc2, acc3);

  // stats: quad-mates identical; strides 4..32 sum the 16 pixel slots once
  float ls[4] = {acc0, acc1, acc2, acc3};
#pragma unroll
  for (int c = 0; c < 4; ++c) {
    float sv = ls[c], qv = ls[c] * ls[c];
#pragma unroll
    for (int d = 4; d < 64; d <<= 1) { sv += __shfl_down(sv, d); qv += __shfl_down(qv, d); }
    if (lane == 0) {
      part[c * 16384 + gwave]       = sv;
      part[(4 + c) * 16384 + gwave] = qv;
    }
  }
}

// ---------------- K5: fused VQ -------------------------------------------
__global__ __launch_bounds__(256) void k_vq(
    const float* __restrict__ y2, const float* __restrict__ bnp2,
    const float* __restrict__ pw, const float* __restrict__ pb,
    const float* __restrict__ cb, const float* __restrict__ postw,
    const float* __restrict__ postb, float* __restrict__ h3,
    float* __restrict__ lpart)
{
  const int tid = threadIdx.x;
  const int pos = blockIdx.x * 256 + tid;     // < 262,144
  float4 v = *(const float4*)(y2 + (size_t)pos * 4);
  float aa0 = fmaxf(fmaf(v.x, bnp2[0], bnp2[4]), 0.f);
  float aa1 = fmaxf(fmaf(v.y, bnp2[1], bnp2[5]), 0.f);
  float aa2 = fmaxf(fmaf(v.z, bnp2[2], bnp2[6]), 0.f);
  float aa3 = fmaxf(fmaf(v.w, bnp2[3], bnp2[7]), 0.f);
  float z0 = pb[0] + aa0*pw[0] + aa1*pw[1] + aa2*pw[2] + aa3*pw[3];
  float z1 = pb[1] + aa0*pw[4] + aa1*pw[5] + aa2*pw[6] + aa3*pw[7];

  float best = 3.4e38f, q0 = 0.f, q1 = 0.f;
#pragma unroll
  for (int k = 0; k < 3; ++k) {
    float c0 = cb[2 * k], c1 = cb[2 * k + 1];
    float dx = z0 - c0, dy = z1 - c1;
    float d = dx * dx + dy * dy;
    if (d < best) { best = d; q0 = c0; q1 = c1; }   // strict < == first-min
  }
  float dl = (q0 - z0) * (q0 - z0) + (q1 - z1) * (q1 - z1);

  float4 hv;
  hv.x = fmaf(q0, postw[0], fmaf(q1, postw[1], postb[0]));
  hv.y = fmaf(q0, postw[2], fmaf(q1, postw[3], postb[1]));
  hv.z = fmaf(q0, postw[4], fmaf(q1, postw[5], postb[2]));
  hv.w = fmaf(q0, postw[6], fmaf(q1, postw[7], postb[3]));
  *(float4*)(h3 + (size_t)pos * 4) = hv;

  float s = dl;
#pragma unroll
  for (int d = 32; d > 0; d >>= 1) s += __shfl_down(s, d);
  __shared__ float ws4[4];
  if ((tid & 63) == 0) ws4[tid >> 6] = s;
  __syncthreads();
  if (tid == 0) lpart[blockIdx.x] = (ws4[0] + ws4[1]) + (ws4[2] + ws4[3]);
}

__global__ __launch_bounds__(256) void k_lossfin(
    const float* __restrict__ lpart, float* __restrict__ outp)
{
  const int tid = threadIdx.x;
  float s = lpart[tid] + lpart[tid + 256] + lpart[tid + 512] + lpart[tid + 768];
#pragma unroll
  for (int d = 32; d > 0; d >>= 1) s += __shfl_down(s, d);
  __shared__ float ws4[4];
  if ((tid & 63) == 0) ws4[tid >> 6] = s;
  __syncthreads();
  if (tid == 0) {
    double tot = (double)ws4[0] + (double)ws4[1] + (double)ws4[2] + (double)ws4[3];
    outp[0] = (float)(1.2 * tot / 524288.0);   // (1+BETA) * mean over B*N*C
  }
}

// ---------------- K7: convT1 (4->16) co-split + stats (P=16) ---------------
__global__ __launch_bounds__(256) void k_convt1(
    const float* __restrict__ h3, const float* __restrict__ w,
    const float* __restrict__ bias, float* __restrict__ h4,
    float* __restrict__ part)
{
  __shared__ float s_w[1024];   // [k16][ci4][co16]
  __shared__ float s_b[16];
  const int tid = threadIdx.x;
  for (int i = tid; i < 1024; i += 256) {
    int co = i & 15, ci = (i >> 4) & 3, k = i >> 6;
    int kh = k >> 2, kw = k & 3;
    s_w[i] = w[((co * 4 + ci) * 4 + kh) * 4 + kw];
  }
  if (tid < 16) s_b[tid] = bias[tid];
  __syncthreads();

  const int lane = tid & 63;
  const int cb = lane & 3;
  const int psl = lane >> 2;
  const int gwave = (blockIdx.x << 2) | (tid >> 6);   // 4096 waves
  const int base = gwave << 8;              // 256 pixels per wave
  const int n = base >> 14;
  const float* hb = h3 + (size_t)n * 16384;
  const float4* s_w4 = (const float4*)s_w;   // idx = k*16 + ci*4 + cb
  const float4 bv = ((const float4*)s_b)[cb];

  float lsum[4] = {0.f, 0.f, 0.f, 0.f}, lsq[4] = {0.f, 0.f, 0.f, 0.f};

#pragma unroll 1
  for (int i = 0; i < 16; ++i) {
    const int pos = base + (i << 4) + psl;
    const int r = pos & 16383;
    const int oh = r >> 7, ow = r & 127;
    const int ohp = oh & 1, owp = ow & 1;

    float a0 = bv.x, a1 = bv.y, a2 = bv.z, a3 = bv.w;
#pragma unroll
    for (int th = 0; th < 2; ++th) {
      int kh = th * 2 + ohp;
      int ih = (oh + kh - 2) >> 1;
      bool okh = (unsigned)ih < 64u;
#pragma unroll
      for (int tw = 0; tw < 2; ++tw) {
        int kw = tw * 2 + owp;
        int iw = (ow + kw - 2) >> 1;
        bool ok = okh && ((unsigned)iw < 64u);
        if (ok) {
          float4 v = *(const float4*)(hb + (ih * 64 + iw) * 4);
          int k16 = (kh * 4 + kw) * 16;
          float4 w0 = s_w4[k16 + 0 * 4 + cb];
          float4 w1 = s_w4[k16 + 1 * 4 + cb];
          float4 w2 = s_w4[k16 + 2 * 4 + cb];
          float4 w3 = s_w4[k16 + 3 * 4 + cb];
          a0 = fmaf(v.x, w0.x, fmaf(v.y, w1.x, fmaf(v.z, w2.x, fmaf(v.w, w3.x, a0))));
          a1 = fmaf(v.x, w0.y, fmaf(v.y, w1.y, fmaf(v.z, w2.y, fmaf(v.w, w3.y, a1))));
          a2 = fmaf(v.x, w0.z, fmaf(v.y, w1.z, fmaf(v.z, w2.z, fmaf(v.w, w3.z, a2))));
          a3 = fmaf(v.x, w0.w, fmaf(v.y, w1.w, fmaf(v.z, w2.w, fmaf(v.w, w3.w, a3))));
        }
      }
    }
    *(float4*)(h4 + (size_t)pos * 16 + cb * 4) = make_float4(a0, a1, a2, a3);
    lsum[0] += a0; lsum[1] += a1; lsum[2] += a2; lsum[3] += a3;
    lsq[0] = fmaf(a0, a0, lsq[0]); lsq[1] = fmaf(a1, a1, lsq[1]);
    lsq[2] = fmaf(a2, a2, lsq[2]); lsq[3] = fmaf(a3, a3, lsq[3]);
  }

#pragma unroll
  for (int j = 0; j < 4; ++j) {
    float sv = lsum[j], qv = lsq[j];
#pragma unroll
    for (int d = 4; d < 64; d <<= 1) { sv += __shfl_down(sv, d); qv += __shfl_down(qv, d); }
    if (lane < 4) {
      part[(lane * 4 + j) * 4096 + gwave]      = sv;
      part[(16 + lane * 4 + j) * 4096 + gwave] = qv;
    }
  }
}

// ---------------- K9: convT2 (16->1), LDS-tiled, XCD-swizzled --------------
__global__ __launch_bounds__(256) void k_convt2(
    const float* __restrict__ h4, const float* __restrict__ w,
    const float* __restrict__ bias, const float* __restrict__ bnp,
    float* __restrict__ out)
{
  __shared__ float4 s_t[4][18][19];
  __shared__ float s_w[256];     // [ci16][kh4][kw4]
  const int tid = threadIdx.x;
  s_w[tid] = w[tid];

  // bijective XCD swizzle: grid 4096 = 8 * 512
  const int bx = ((blockIdx.x & 7) << 9) | (blockIdx.x >> 3);
  const int n = bx >> 6;
  const int tile = bx & 63;
  const int ta = ((tile >> 3) << 4);   // input tile origin row
  const int tb = ((tile & 7) << 4);    // input tile origin col
  const float* hb = h4 + (size_t)n * 262144;

  for (int i = tid; i < 1296; i += 256) {     // 324 positions x 4 groups
    int g = i & 3, p = i >> 2;
    int row = p / 18, col = p - row * 18;
    int ih = ta - 1 + row, iw = tb - 1 + col;
    float4 t = make_float4(0.f, 0.f, 0.f, 0.f);
    if (((unsigned)ih < 128u) && ((unsigned)iw < 128u)) {
      float4 v   = *(const float4*)(hb + ((ih << 7) + iw) * 16 + (g << 2));
      float4 scv = *(const float4*)(bnp + 40 + (g << 2));
      float4 shv = *(const float4*)(bnp + 56 + (g << 2));
      t.x = fmaxf(fmaf(v.x, scv.x, shv.x), 0.f);
      t.y = fmaxf(fmaf(v.y, scv.y, shv.y), 0.f);
      t.z = fmaxf(fmaf(v.z, scv.z, shv.z), 0.f);
      t.w = fmaxf(fmaf(v.w, scv.w, shv.w), 0.f);
    }
    s_t[g][row][col] = t;
  }
  __syncthreads();

  const int a = tid >> 4, b = tid & 15;
  const float4* s_w4 = (const float4*)s_w;
  float acc00 = 0.f, acc01 = 0.f, acc10 = 0.f, acc11 = 0.f;

#pragma unroll
  for (int g = 0; g < 4; ++g) {
    float4 v00 = s_t[g][a  ][b  ], v01 = s_t[g][a  ][b+1], v02 = s_t[g][a  ][b+2];
    float4 v10 = s_t[g][a+1][b  ], v11 = s_t[g][a+1][b+1], v12 = s_t[g][a+1][b+2];
    float4 v20 = s_t[g][a+2][b  ], v21 = s_t[g][a+2][b+1], v22 = s_t[g][a+2][b+2];
#pragma unroll
    for (int j = 0; j < 4; ++j) {
      int ci = g * 4 + j;
      float4 r0 = s_w4[ci*4+0], r1 = s_w4[ci*4+1];
      float4 r2 = s_w4[ci*4+2], r3 = s_w4[ci*4+3];
      float a00 = (j==0)?v00.x:(j==1)?v00.y:(j==2)?v00.z:v00.w;
      float a01 = (j==0)?v01.x:(j==1)?v01.y:(j==2)?v01.z:v01.w;
      float a02 = (j==0)?v02.x:(j==1)?v02.y:(j==2)?v02.z:v02.w;
      float a10 = (j==0)?v10.x:(j==1)?v10.y:(j==2)?v10.z:v10.w;
      float a11 = (j==0)?v11.x:(j==1)?v11.y:(j==2)?v11.z:v11.w;
      float a12 = (j==0)?v12.x:(j==1)?v12.y:(j==2)?v12.z:v12.w;
      float a20 = (j==0)?v20.x:(j==1)?v20.y:(j==2)?v20.z:v20.w;
      float a21 = (j==0)?v21.x:(j==1)?v21.y:(j==2)?v21.z:v21.w;
      float a22 = (j==0)?v22.x:(j==1)?v22.y:(j==2)?v22.z:v22.w;
      acc00 += a00*r0.x + a01*r0.z + a10*r2.x + a11*r2.z;
      acc01 += a01*r0.y + a02*r0.w + a11*r2.y + a12*r2.w;
      acc10 += a10*r1.x + a11*r1.z + a20*r3.x + a21*r3.z;
      acc11 += a11*r1.y + a12*r1.w + a21*r3.y + a22*r3.w;
    }
  }
  const float bv = bias[0];
  const int A = ta + a, B = tb + b;
  float* ob = out + n * 65536 + (2 * A) * 256 + 2 * B;
  *(float2*)ob         = make_float2(acc00 + bv, acc01 + bv);
  *(float2*)(ob + 256) = make_float2(acc10 + bv, acc11 + bv);
}

// ---------------------------------------------------------------------------
extern "C" void kernel_launch(void* const* d_in, const int* in_sizes, int n_in,
                              void* d_out, int out_size, void* d_ws, size_t ws_size,
                              hipStream_t stream)
{
  const float* x      = (const float*)d_in[0];
  const float* enc_w1 = (const float*)d_in[1];
  const float* enc_b1 = (const float*)d_in[2];
  const float* bn1_g  = (const float*)d_in[3];
  const float* bn1_b  = (const float*)d_in[4];
  const float* enc_w2 = (const float*)d_in[5];
  const float* enc_b2 = (const float*)d_in[6];
  const float* bn2_g  = (const float*)d_in[7];
  const float* bn2_b  = (const float*)d_in[8];
  const float* pre_w  = (const float*)d_in[9];
  const float* pre_b  = (const float*)d_in[10];
  const float* cb     = (const float*)d_in[11];
  const float* post_w = (const float*)d_in[12];
  const float* post_b = (const float*)d_in[13];
  const float* dec_w1 = (const float*)d_in[14];
  const float* dec_b1 = (const float*)d_in[15];
  const float* bn3_g  = (const float*)d_in[16];
  const float* bn3_b  = (const float*)d_in[17];
  const float* dec_w2 = (const float*)d_in[18];
  const float* dec_b2 = (const float*)d_in[19];

  float* ws  = (float*)d_ws;
  float* y1  = ws;                       // 16,777,216 f (NHWC) -- reused as h4
  float* y2  = ws + 16777216;            //  1,048,576 f
  float* h3  = ws + 17825792;            //  1,048,576 f
  float* p1  = ws + 18874368;            //    131,072 f ([32][4096]) -- also p3
  float* p2  = ws + 19005440;            //    131,072 f ([8][16384])
  float* lp  = ws + 19136512;            //      1,024 f
  float* bnp = ws + 19137536;            //         72 f (sc1,sh1,sc2,sh2,sc3,sh3)
  float* h4  = y1;
  float* p3  = p1;
  float* out = (float*)d_out;

  k_conv1<<<1024, 256, 0, stream>>>(x, enc_w1, enc_b1, y1, p1);
  k_bnredN<16, 4096><<<16, 256, 0, stream>>>(p1, bn1_g, bn1_b, bnp, bnp + 16, 1.0 / 1048576.0);
  k_conv2<<<4096, 256, 0, stream>>>(y1, enc_w2, enc_b2, bnp, y2, p2);
  k_bnredN<4, 16384><<<4, 256, 0, stream>>>(p2, bn2_g, bn2_b, bnp + 32, bnp + 36, 1.0 / 262144.0);
  k_vq<<<1024, 256, 0, stream>>>(y2, bnp + 32, pre_w, pre_b, cb, post_w, post_b, h3, lp);
  k_lossfin<<<1, 256, 0, stream>>>(lp, out + 4194304);
  k_convt1<<<1024, 256, 0, stream>>>(h3, dec_w1, dec_b1, h4, p3);
  k_bnredN<16, 4096><<<16, 256, 0, stream>>>(p3, bn3_g, bn3_b, bnp + 40, bnp + 56, 1.0 / 1048576.0);
  k_convt2<<<4096, 256, 0, stream>>>(h4, dec_w2, dec_b2, bnp, out);
}